// Round 5
// baseline (1201.667 us; speedup 1.0000x reference)
//
#include <hip/hip_runtime.h>
#include <hip/hip_bf16.h>

// LlamaAttentionWithLora on MI355X — round 5.
// GEMM: BM=128,BN=256,BK=64 8-wave 2-phase counted-vmcnt template (better grid quantization:
// QKV = 1008 blocks = 3.94 rounds @ 1 block/CU vs 528 = 2.06-in-3 before) + XCD swizzle.
// lora_add(q,k,v) + RoPE + bf16 emit fused into one pass.

#define H_    4096
#define NH_   32
#define HD_   128
#define T_    2592
#define DOFF_ 2560
#define DEC_  32
#define LMAX_ 512
#define RANK_ 16
#define MPAD_ 2816   // hsb rows allocated (>= 21*128 = 2688 staged)

__constant__ float SCALE_ = 0.08838834764831845f; // 128^-0.5

typedef __bf16 bf16x8 __attribute__((ext_vector_type(8)));
typedef __bf16 bf16x4 __attribute__((ext_vector_type(4)));
typedef float  f32x4  __attribute__((ext_vector_type(4)));

__device__ __forceinline__ void async_cp16(const __bf16* g, __bf16* l) {
    __builtin_amdgcn_global_load_lds(
        (const __attribute__((address_space(1))) void*)g,
        (__attribute__((address_space(3))) void*)l, 16, 0, 0);
}

// ---------------------------------------------------------------- f32 -> bf16 convert
__global__ __launch_bounds__(256)
void convert_bf16_kernel(const float* __restrict__ src, __bf16* __restrict__ dst, int n8)
{
    const int stride = gridDim.x * blockDim.x;
    for (int i = blockIdx.x * blockDim.x + threadIdx.x; i < n8; i += stride) {
        float4 a = ((const float4*)src)[i * 2];
        float4 b = ((const float4*)src)[i * 2 + 1];
        bf16x8 w;
        w[0] = (__bf16)a.x; w[1] = (__bf16)a.y; w[2] = (__bf16)a.z; w[3] = (__bf16)a.w;
        w[4] = (__bf16)b.x; w[5] = (__bf16)b.y; w[6] = (__bf16)b.z; w[7] = (__bf16)b.w;
        ((bf16x8*)dst)[i] = w;
    }
}

// ---------------------------------------------------------------- f32 [K][N] -> bf16 [N][K]
__global__ __launch_bounds__(256)
void transpose_bf16_kernel(const float* __restrict__ W0, const float* __restrict__ W1,
                           const float* __restrict__ W2,
                           __bf16* __restrict__ T0, __bf16* __restrict__ T1, __bf16* __restrict__ T2)
{
    const float* W = (blockIdx.z == 0) ? W0 : (blockIdx.z == 1 ? W1 : W2);
    __bf16* To     = (blockIdx.z == 0) ? T0 : (blockIdx.z == 1 ? T1 : T2);
    __shared__ float s[32][33];
    const int bx = blockIdx.x * 32;
    const int by = blockIdx.y * 32;
    const int r  = threadIdx.x >> 3;
    const int c4 = (threadIdx.x & 7) * 4;
    float4 v = *(const float4*)&W[(size_t)(by + r) * H_ + bx + c4];
    s[r][c4] = v.x; s[r][c4 + 1] = v.y; s[r][c4 + 2] = v.z; s[r][c4 + 3] = v.w;
    __syncthreads();
    bf16x4 o;
    o[0] = (__bf16)s[c4 + 0][r]; o[1] = (__bf16)s[c4 + 1][r];
    o[2] = (__bf16)s[c4 + 2][r]; o[3] = (__bf16)s[c4 + 3][r];
    *(bf16x4*)&To[(size_t)(bx + r) * H_ + by + c4] = o;
}

// ---------------------------------------------------------------- V transpose per head
__global__ __launch_bounds__(256)
void transpose_v_kernel(const float* __restrict__ v, __bf16* __restrict__ vT)
{
    __shared__ float s[64][129];
    const int tb = blockIdx.x;
    const int h  = blockIdx.y;
    const int tid = threadIdx.x;
    #pragma unroll
    for (int i = 0; i < 8; ++i) {
        const int idx = i * 256 + tid;
        const int row = idx >> 5;
        const int c4  = (idx & 31) * 4;
        *(float4*)&s[row][c4] = *(const float4*)&v[(size_t)(tb * 64 + row) * H_ + h * HD_ + c4];
    }
    __syncthreads();
    #pragma unroll
    for (int i = 0; i < 4; ++i) {
        const int idx = i * 256 + tid;
        const int d = idx >> 3;
        const int c = idx & 7;
        bf16x8 w;
        #pragma unroll
        for (int j = 0; j < 8; ++j) w[j] = (__bf16)s[c * 8 + j][d];
        *(bf16x8*)&vT[(size_t)(h * HD_ + d) * T_ + tb * 64 + c * 8] = w;
    }
}

// ---------------------------------------------------------------- GEMM 128x256, BK=64, 2-phase/K-tile
// C = A @ Bt^T. A: bf16 rm (rows padded). Bt: 4096x4096 bf16 [n][k]. Grid (21,16,z).
__global__ __launch_bounds__(512, 2)
void gemm_mfma8(const __bf16* __restrict__ A,
                const __bf16* __restrict__ Bt0, const __bf16* __restrict__ Bt1,
                const __bf16* __restrict__ Bt2,
                float* __restrict__ C0, float* __restrict__ C1, float* __restrict__ C2, int M)
{
    const __bf16* Bt; float* C;
    if      (blockIdx.z == 0) { Bt = Bt0; C = C0; }
    else if (blockIdx.z == 1) { Bt = Bt1; C = C1; }
    else                      { Bt = Bt2; C = C2; }

    // XCD-aware swizzle over the 21x16 = 336 xy-grid (336 % 8 == 0 -> simple bijection)
    int bid = blockIdx.y * 21 + blockIdx.x;
    bid = (bid & 7) * 42 + (bid >> 3);
    const int bm0 = (bid % 21) * 128;
    const int bn0 = (bid / 21) * 256;

    // A: [buf][kh][128*32] 8KB regions; B: [buf][kh][256*32] 16KB regions. Total 96KB.
    __shared__ __align__(16) __bf16 Asl[2][2][128 * 32];
    __shared__ __align__(16) __bf16 Bsl[2][2][256 * 32];

    const int tid = threadIdx.x, lane = tid & 63, wid = tid >> 6;
    const int wr = wid >> 2, wc = wid & 3;          // 2M x 4N waves, wave tile 64x64
    const int fr = lane & 15, fq = lane >> 4;
    const bool mlive = (bm0 + wr * 64) < M;

    // staging geometry (chunk = 8 bf16, swizzle p = c ^ ((row>>1)&3))
    const int cA  = wid * 64 + lane;                // A: 512 chunks = 128 rows x 4
    const int rA  = cA >> 2, gA = ((cA & 3) ^ ((rA >> 1) & 3)) * 8;
    const int cB0 = wid * 128 + lane;               // B: 1024 chunks = 256 rows x 4
    const int rB0 = cB0 >> 2, gB0 = ((cB0 & 3) ^ ((rB0 >> 1) & 3)) * 8;
    const int cB1 = cB0 + 64;
    const int rB1 = cB1 >> 2, gB1 = ((cB1 & 3) ^ ((rB1 >> 1) & 3)) * 8;

    const __bf16* Ab = A  + (size_t)bm0 * H_;
    const __bf16* Bb = Bt + (size_t)bn0 * H_;

    auto stage = [&](int buf, int kh, int kt1) {    // 3 loads: 1 A + 2 B
        const int kb = kt1 * 64 + kh * 32;
        async_cp16(Ab + (size_t)rA * H_ + kb + gA, &Asl[buf][kh][wid * 512]);
        __bf16* dstB = &Bsl[buf][kh][wid * 1024];
        async_cp16(Bb + (size_t)rB0 * H_ + kb + gB0, dstB);
        async_cp16(Bb + (size_t)rB1 * H_ + kb + gB1, dstB + 512);
    };
    auto rdA = [&](int buf, int kh, int mi) -> bf16x8 {
        const int row = wr * 64 + mi * 16 + fr;
        return *(const bf16x8*)&Asl[buf][kh][row * 32 + ((fq ^ ((row >> 1) & 3)) << 3)];
    };
    auto rdB = [&](int buf, int kh, int nj) -> bf16x8 {
        const int row = wc * 64 + nj * 16 + fr;
        return *(const bf16x8*)&Bsl[buf][kh][row * 32 + ((fq ^ ((row >> 1) & 3)) << 3)];
    };

    f32x4 acc[4][4] = {};

    // prologue: tile 0 both halves (6 loads); land kh0, keep kh1 in flight
    stage(0, 0, 0);
    stage(0, 1, 0);
    asm volatile("s_waitcnt vmcnt(3)");
    __builtin_amdgcn_sched_barrier(0);
    __builtin_amdgcn_s_barrier();

    const int NT = H_ / 64;
    for (int kt = 0; kt < NT; ++kt) {
        const int cur = kt & 1, nb = cur ^ 1;
        const bool pf = (kt + 1 < NT);
        bf16x8 af[4], bf[4];

        #pragma unroll
        for (int kh = 0; kh < 2; ++kh) {
            if (mlive) {
                #pragma unroll
                for (int mi = 0; mi < 4; ++mi) af[mi] = rdA(cur, kh, mi);
                #pragma unroll
                for (int nj = 0; nj < 4; ++nj) bf[nj] = rdB(cur, kh, nj);
            }
            if (pf) {
                stage(nb, kh, kt + 1);
                asm volatile("s_waitcnt vmcnt(3)");   // kh0: land cur-kh1; kh1: land nb-kh0
            } else {
                asm volatile("s_waitcnt vmcnt(0)");
            }
            __builtin_amdgcn_sched_barrier(0);
            __builtin_amdgcn_s_barrier();
            asm volatile("s_waitcnt lgkmcnt(0)");
            __builtin_amdgcn_sched_barrier(0);
            __builtin_amdgcn_s_setprio(1);
            if (mlive) {
                #pragma unroll
                for (int mi = 0; mi < 4; ++mi)
                    #pragma unroll
                    for (int nj = 0; nj < 4; ++nj)
                        acc[mi][nj] = __builtin_amdgcn_mfma_f32_16x16x32_bf16(af[mi], bf[nj], acc[mi][nj], 0, 0, 0);
            }
            __builtin_amdgcn_s_setprio(0);
            __builtin_amdgcn_s_barrier();
        }
    }

    if (mlive) {
        #pragma unroll
        for (int mi = 0; mi < 4; ++mi)
            #pragma unroll
            for (int nj = 0; nj < 4; ++nj)
                #pragma unroll
                for (int r = 0; r < 4; ++r) {
                    const int row = bm0 + wr * 64 + mi * 16 + fq * 4 + r;
                    const int col = bn0 + wc * 64 + nj * 16 + fr;
                    if (row < M) C[(size_t)row * H_ + col] = acc[mi][nj][r];
                }
    }
}

// ---------------------------------------------------------------- LoRA stage 1 (f32 X)
__global__ __launch_bounds__(256)
void lora_tmp_kernel(const float* __restrict__ X,
                     const float* __restrict__ la0, const float* __restrict__ la1,
                     const float* __restrict__ la2, float* __restrict__ tmp)
{
    const int r = blockIdx.x;
    const int z = blockIdx.y;
    const float* la = (z == 0) ? la0 : (z == 1 ? la1 : la2);
    const int si = (r < 648) ? 0 : (r < 1296 ? 1 : (r < 1944 ? 2 : 3));
    const float* wa = la + (size_t)si * H_ * RANK_;
    const int c    = threadIdx.x & 15;
    const int part = threadIdx.x >> 4;
    const float* xr = X + (size_t)r * H_;
    float s = 0.f;
    const int h0 = part * 256;
    for (int h = h0; h < h0 + 256; ++h) s += xr[h] * wa[(size_t)h * RANK_ + c];
    __shared__ float red[16][17];
    red[part][c] = s;
    __syncthreads();
    if (threadIdx.x < 16) {
        float t = 0.f;
        #pragma unroll
        for (int p = 0; p < 16; ++p) t += red[p][threadIdx.x];
        tmp[((size_t)z * T_ + r) * RANK_ + threadIdx.x] = t;
    }
}

// ---------------------------------------------------------------- LoRA stage 1 (bf16 X)
__global__ __launch_bounds__(256)
void lora_tmp_bf16_kernel(const __bf16* __restrict__ X,
                          const float* __restrict__ la, float* __restrict__ tmp)
{
    const int r = blockIdx.x;
    const int si = (r < 648) ? 0 : (r < 1296 ? 1 : (r < 1944 ? 2 : 3));
    const float* wa = la + (size_t)si * H_ * RANK_;
    const int c    = threadIdx.x & 15;
    const int part = threadIdx.x >> 4;
    const __bf16* xr = X + (size_t)r * H_;
    float s = 0.f;
    const int h0 = part * 256;
    for (int h = h0; h < h0 + 256; ++h) s += (float)xr[h] * wa[(size_t)h * RANK_ + c];
    __shared__ float red[16][17];
    red[part][c] = s;
    __syncthreads();
    if (threadIdx.x < 16) {
        float t = 0.f;
        #pragma unroll
        for (int p = 0; p < 16; ++p) t += red[p][threadIdx.x];
        tmp[(size_t)r * RANK_ + threadIdx.x] = t;
    }
}

// ---------------------------------------------------------------- LoRA stage 2 (O-proj only)
__global__ __launch_bounds__(256)
void lora_add_kernel(const float* __restrict__ tmp,
                     const float* __restrict__ lb0, const float* __restrict__ lb1,
                     const float* __restrict__ lb2,
                     float* __restrict__ Y0, float* __restrict__ Y1, float* __restrict__ Y2)
{
    const int z = blockIdx.z;
    const float* lb = (z == 0) ? lb0 : (z == 1 ? lb1 : lb2);
    float* Y = (z == 0) ? Y0 : (z == 1 ? Y1 : Y2);
    const int r = blockIdx.x;
    const int n = blockIdx.y * 256 + threadIdx.x;
    const int si = (r < 648) ? 0 : (r < 1296 ? 1 : (r < 1944 ? 2 : 3));
    const float* wb = lb + (size_t)si * RANK_ * H_;
    __shared__ float tl[16];
    if (threadIdx.x < 16) tl[threadIdx.x] = tmp[((size_t)z * T_ + r) * RANK_ + threadIdx.x];
    __syncthreads();
    float s = 0.f;
    #pragma unroll
    for (int c = 0; c < 16; ++c) s += tl[c] * wb[(size_t)c * H_ + n];
    Y[(size_t)r * H_ + n] += s;
}

// ---------------------------------------------------------------- RoPE tables
__global__ void rope_table_kernel(float* __restrict__ cost, float* __restrict__ sint)
{
    const int p = blockIdx.x;
    const int i = threadIdx.x;
    const float inv = powf(10000.f, -(float)(2 * i) / (float)HD_);
    const float a = (float)p * inv;
    cost[p * 64 + i] = cosf(a);
    sint[p * 64 + i] = sinf(a);
}

// ---------------------------------------------------------------- fused: Y += lora, rope(q,k), bf16 emit
// One block per row. Threads: h = tid>>3 (head), sub = tid&7 -> elems i0..i0+7 and +64.
__global__ __launch_bounds__(256)
void lora_rope_fused(float* __restrict__ q, float* __restrict__ k, float* __restrict__ v,
                     const float* __restrict__ tmp,
                     const float* __restrict__ lbq, const float* __restrict__ lbk,
                     const float* __restrict__ lbv,
                     const int* __restrict__ kv_lens,
                     const float* __restrict__ cost, const float* __restrict__ sint,
                     __bf16* __restrict__ q16, __bf16* __restrict__ k16)
{
    const int r = blockIdx.x;
    const int si = (r < 648) ? 0 : (r < 1296 ? 1 : (r < 1944 ? 2 : 3));
    int pos; bool dok;
    if (r < DOFF_) {
        if      (r < 1024) pos = r;
        else if (r < 1536) pos = r - 1024;
        else if (r < 2304) pos = r - 1536;
        else               pos = r - 2304;
        dok = true;
    } else {
        pos = kv_lens[r - DOFF_];
        dok = false;
    }

    __shared__ float tq[16], tk[16], tv[16];
    const int tid = threadIdx.x;
    if (tid < 16)      tq[tid]      = tmp[(size_t)r * RANK_ + tid];
    else if (tid < 32) tk[tid - 16] = tmp[((size_t)T_ + r) * RANK_ + (tid - 16)];
    else if (tid < 48) tv[tid - 32] = tmp[((size_t)2 * T_ + r) * RANK_ + (tid - 32)];
    __syncthreads();

    const int h = tid >> 3, sub = tid & 7;
    const int i0 = sub * 8;
    const size_t b1 = (size_t)r * H_ + h * HD_ + i0;
    const size_t b2 = b1 + 64;
    const int n1 = h * HD_ + i0;

    float cs[8], sn[8];
    #pragma unroll
    for (int j = 0; j < 8; ++j) { cs[j] = cost[pos * 64 + i0 + j]; sn[j] = sint[pos * 64 + i0 + j]; }

    float y1[8], y2[8];
    // ---------------- Q
    {
        *(float4*)&y1[0] = *(const float4*)&q[b1]; *(float4*)&y1[4] = *(const float4*)&q[b1 + 4];
        *(float4*)&y2[0] = *(const float4*)&q[b2]; *(float4*)&y2[4] = *(const float4*)&q[b2 + 4];
        const float* wb = lbq + (size_t)si * RANK_ * H_;
        #pragma unroll
        for (int c = 0; c < 16; ++c) {
            const float tc = tq[c];
            const float* wr_ = wb + (size_t)c * H_ + n1;
            float4 w0 = *(const float4*)&wr_[0],  w1 = *(const float4*)&wr_[4];
            float4 w2 = *(const float4*)&wr_[64], w3 = *(const float4*)&wr_[68];
            y1[0] += tc * w0.x; y1[1] += tc * w0.y; y1[2] += tc * w0.z; y1[3] += tc * w0.w;
            y1[4] += tc * w1.x; y1[5] += tc * w1.y; y1[6] += tc * w1.z; y1[7] += tc * w1.w;
            y2[0] += tc * w2.x; y2[1] += tc * w2.y; y2[2] += tc * w2.z; y2[3] += tc * w2.w;
            y2[4] += tc * w3.x; y2[5] += tc * w3.y; y2[6] += tc * w3.z; y2[7] += tc * w3.w;
        }
        float z1[8], z2[8];
        bf16x8 o1, o2;
        #pragma unroll
        for (int j = 0; j < 8; ++j) {
            z1[j] = y1[j] * cs[j] - y2[j] * sn[j];
            z2[j] = y2[j] * cs[j] + y1[j] * sn[j];
            o1[j] = (__bf16)z1[j]; o2[j] = (__bf16)z2[j];
        }
        *(float4*)&q[b1] = *(float4*)&z1[0]; *(float4*)&q[b1 + 4] = *(float4*)&z1[4];
        *(float4*)&q[b2] = *(float4*)&z2[0]; *(float4*)&q[b2 + 4] = *(float4*)&z2[4];
        *(bf16x8*)&q16[b1] = o1; *(bf16x8*)&q16[b2] = o2;
    }
    // ---------------- K
    {
        *(float4*)&y1[0] = *(const float4*)&k[b1]; *(float4*)&y1[4] = *(const float4*)&k[b1 + 4];
        *(float4*)&y2[0] = *(const float4*)&k[b2]; *(float4*)&y2[4] = *(const float4*)&k[b2 + 4];
        const float* wb = lbk + (size_t)si * RANK_ * H_;
        #pragma unroll
        for (int c = 0; c < 16; ++c) {
            const float tc = tk[c];
            const float* wr_ = wb + (size_t)c * H_ + n1;
            float4 w0 = *(const float4*)&wr_[0],  w1 = *(const float4*)&wr_[4];
            float4 w2 = *(const float4*)&wr_[64], w3 = *(const float4*)&wr_[68];
            y1[0] += tc * w0.x; y1[1] += tc * w0.y; y1[2] += tc * w0.z; y1[3] += tc * w0.w;
            y1[4] += tc * w1.x; y1[5] += tc * w1.y; y1[6] += tc * w1.z; y1[7] += tc * w1.w;
            y2[0] += tc * w2.x; y2[1] += tc * w2.y; y2[2] += tc * w2.z; y2[3] += tc * w2.w;
            y2[4] += tc * w3.x; y2[5] += tc * w3.y; y2[6] += tc * w3.z; y2[7] += tc * w3.w;
        }
        float z1[8], z2[8];
        bf16x8 o1, o2;
        #pragma unroll
        for (int j = 0; j < 8; ++j) {
            if (dok) {
                z1[j] = y1[j] * cs[j] - y2[j] * sn[j];
                z2[j] = y2[j] * cs[j] + y1[j] * sn[j];
            } else {
                z1[j] = y1[j]; z2[j] = y2[j];
            }
            o1[j] = (__bf16)z1[j]; o2[j] = (__bf16)z2[j];
        }
        *(float4*)&k[b1] = *(float4*)&z1[0]; *(float4*)&k[b1 + 4] = *(float4*)&z1[4];
        *(float4*)&k[b2] = *(float4*)&z2[0]; *(float4*)&k[b2 + 4] = *(float4*)&z2[4];
        *(bf16x8*)&k16[b1] = o1; *(bf16x8*)&k16[b2] = o2;
    }
    // ---------------- V (no rope)
    {
        *(float4*)&y1[0] = *(const float4*)&v[b1]; *(float4*)&y1[4] = *(const float4*)&v[b1 + 4];
        *(float4*)&y2[0] = *(const float4*)&v[b2]; *(float4*)&y2[4] = *(const float4*)&v[b2 + 4];
        const float* wb = lbv + (size_t)si * RANK_ * H_;
        #pragma unroll
        for (int c = 0; c < 16; ++c) {
            const float tc = tv[c];
            const float* wr_ = wb + (size_t)c * H_ + n1;
            float4 w0 = *(const float4*)&wr_[0],  w1 = *(const float4*)&wr_[4];
            float4 w2 = *(const float4*)&wr_[64], w3 = *(const float4*)&wr_[68];
            y1[0] += tc * w0.x; y1[1] += tc * w0.y; y1[2] += tc * w0.z; y1[3] += tc * w0.w;
            y1[4] += tc * w1.x; y1[5] += tc * w1.y; y1[6] += tc * w1.z; y1[7] += tc * w1.w;
            y2[0] += tc * w2.x; y2[1] += tc * w2.y; y2[2] += tc * w2.z; y2[3] += tc * w2.w;
            y2[4] += tc * w3.x; y2[5] += tc * w3.y; y2[6] += tc * w3.z; y2[7] += tc * w3.w;
        }
        *(float4*)&v[b1] = *(float4*)&y1[0]; *(float4*)&v[b1 + 4] = *(float4*)&y1[4];
        *(float4*)&v[b2] = *(float4*)&y2[0]; *(float4*)&v[b2 + 4] = *(float4*)&y2[4];
    }
}

// ---------------------------------------------------------------- prefill attention (MFMA bf16, flash)
__global__ __launch_bounds__(256)
void prefill_attn_mfma(const __bf16* __restrict__ q16, const __bf16* __restrict__ k16,
                       const __bf16* __restrict__ vT, __bf16* __restrict__ attn16)
{
    const int qb = blockIdx.x;
    int soff, qoff;
    if      (qb < 16) { soff = 0;    qoff = qb * 64; }
    else if (qb < 24) { soff = 1024; qoff = (qb - 16) * 64; }
    else if (qb < 36) { soff = 1536; qoff = (qb - 24) * 64; }
    else              { soff = 2304; qoff = (qb - 36) * 64; }
    const int h = blockIdx.y;

    __shared__ __align__(16) __bf16 Kl[64 * 128];
    __shared__ __align__(16) __bf16 Vl[128 * 64];
    __shared__ __align__(16) __bf16 Pl[4][16 * 64];

    const int tid = threadIdx.x, lane = tid & 63, wid = tid >> 6;
    const int fr = lane & 15, fq = lane >> 4;

    const int grow0 = soff + qoff + wid * 16;
    bf16x8 qf[4];
    #pragma unroll
    for (int ks = 0; ks < 4; ++ks)
        qf[ks] = *(const bf16x8*)&q16[(size_t)(grow0 + fr) * H_ + h * HD_ + ks * 32 + fq * 8];

    float m[4], l[4];
    #pragma unroll
    for (int r = 0; r < 4; ++r) { m[r] = -1e30f; l[r] = 0.f; }
    f32x4 o[8] = {};

    const int ntiles = qoff / 64 + 1;
    for (int t = 0; t < ntiles; ++t) {
        const int kt = t * 64;
        #pragma unroll
        for (int i = 0; i < 4; ++i) {
            const int chunk = i * 256 + tid;
            const int row = chunk >> 4, c = chunk & 15;
            async_cp16(k16 + (size_t)(soff + kt + row) * H_ + h * HD_ + ((c ^ (row & 7)) * 8),
                       Kl + (size_t)(i * 256 + wid * 64) * 8);
        }
        #pragma unroll
        for (int i = 0; i < 4; ++i) {
            const int chunk = i * 256 + tid;
            const int row = chunk >> 3, c = chunk & 7;
            async_cp16(vT + (size_t)(h * HD_ + row) * T_ + soff + kt + ((c ^ (row & 7)) * 8),
                       Vl + (size_t)(i * 256 + wid * 64) * 8);
        }
        __syncthreads();

        f32x4 s[4] = {};
        #pragma unroll
        for (int sub = 0; sub < 4; ++sub)
            #pragma unroll
            for (int ks = 0; ks < 4; ++ks) {
                bf16x8 b = *(const bf16x8*)&Kl[(sub * 16 + fr) * 128 + (((ks * 4 + fq) ^ (fr & 7)) * 8)];
                s[sub] = __builtin_amdgcn_mfma_f32_16x16x32_bf16(qf[ks], b, s[sub], 0, 0, 0);
            }

        float p[4][4];
        #pragma unroll
        for (int sub = 0; sub < 4; ++sub)
            #pragma unroll
            for (int r = 0; r < 4; ++r) {
                const int qpos = qoff + wid * 16 + fq * 4 + r;
                const int kpos = kt + sub * 16 + fr;
                p[sub][r] = (kpos <= qpos) ? s[sub][r] * SCALE_ : -1e30f;
            }
        float fsc[4];
        #pragma unroll
        for (int r = 0; r < 4; ++r) {
            float tm = fmaxf(fmaxf(p[0][r], p[1][r]), fmaxf(p[2][r], p[3][r]));
            tm = fmaxf(tm, __shfl_xor(tm, 1));
            tm = fmaxf(tm, __shfl_xor(tm, 2));
            tm = fmaxf(tm, __shfl_xor(tm, 4));
            tm = fmaxf(tm, __shfl_xor(tm, 8));
            const float mn = fmaxf(m[r], tm);
            fsc[r] = __expf(m[r] - mn);
            m[r] = mn;
            float ls = 0.f;
            #pragma unroll
            for (int sub = 0; sub < 4; ++sub) {
                p[sub][r] = __expf(p[sub][r] - mn);
                ls += p[sub][r];
            }
            l[r] = l[r] * fsc[r] + ls;
        }
        #pragma unroll
        for (int c = 0; c < 8; ++c)
            #pragma unroll
            for (int r = 0; r < 4; ++r) o[c][r] *= fsc[r];

        #pragma unroll
        for (int sub = 0; sub < 4; ++sub)
            #pragma unroll
            for (int r = 0; r < 4; ++r) {
                const int qr = fq * 4 + r;
                Pl[wid][qr * 64 + ((sub * 16 + fr) ^ ((qr & 7) << 3))] = (__bf16)p[sub][r];
            }
        bf16x8 pa[2];
        #pragma unroll
        for (int a = 0; a < 2; ++a)
            pa[a] = *(const bf16x8*)&Pl[wid][fr * 64 + (((a * 4 + fq) ^ (fr & 7)) * 8)];

        #pragma unroll
        for (int a = 0; a < 2; ++a)
            #pragma unroll
            for (int c = 0; c < 8; ++c) {
                bf16x8 bv = *(const bf16x8*)&Vl[(c * 16 + fr) * 64 + (((a * 4 + fq) ^ (fr & 7)) * 8)];
                o[c] = __builtin_amdgcn_mfma_f32_16x16x32_bf16(pa[a], bv, o[c], 0, 0, 0);
            }
        __syncthreads();
    }

    float inv[4];
    #pragma unroll
    for (int r = 0; r < 4; ++r) {
        float ls = l[r];
        ls += __shfl_xor(ls, 1); ls += __shfl_xor(ls, 2);
        ls += __shfl_xor(ls, 4); ls += __shfl_xor(ls, 8);
        inv[r] = 1.f / ls;
    }
    #pragma unroll
    for (int c = 0; c < 8; ++c)
        #pragma unroll
        for (int r = 0; r < 4; ++r)
            attn16[(size_t)(grow0 + fq * 4 + r) * H_ + h * HD_ + c * 16 + fr] = (__bf16)(o[c][r] * inv[r]);
}

// ---------------------------------------------------------------- decode attention
__global__ __launch_bounds__(256)
void decode_attn_kernel(const float* __restrict__ qb_, const float* __restrict__ kb_,
                        const float* __restrict__ vb_, const float* __restrict__ kc,
                        const float* __restrict__ vc, const int* __restrict__ kv_lens,
                        const float* __restrict__ cost, const float* __restrict__ sint,
                        __bf16* __restrict__ attn16)
{
    const int b = blockIdx.x, h = blockIdx.y;
    const int kvlen = kv_lens[b];
    const int L = kvlen + 1;
    const int tid = threadIdx.x, lane = tid & 63, w = tid >> 6;

    __shared__ float sc_s[LMAX_];
    __shared__ float red[4];
    __shared__ float oacc[HD_];

    const float* qrow = qb_ + (size_t)(DOFF_ + b) * H_ + h * HD_;
    const float q1 = qrow[lane], q2 = qrow[lane + 64];
    const float* kdrow = kb_ + (size_t)(DOFF_ + b) * H_ + h * HD_;

    for (int l = w; l < L; l += 4) {
        const float* src = (l == kvlen) ? kdrow
                                        : kc + (((size_t)b * LMAX_ + l) * NH_ + h) * HD_;
        const float k1 = src[lane], k2 = src[lane + 64];
        const float c = cost[l * 64 + lane], s = sint[l * 64 + lane];
        float d = q1 * (k1 * c - k2 * s) + q2 * (k2 * c + k1 * s);
        #pragma unroll
        for (int off = 1; off < 64; off <<= 1) d += __shfl_xor(d, off);
        if (lane == 0) sc_s[l] = d * SCALE_;
    }
    __syncthreads();

    float mx = -1e30f;
    for (int i = tid; i < L; i += 256) mx = fmaxf(mx, sc_s[i]);
    #pragma unroll
    for (int off = 1; off < 64; off <<= 1) mx = fmaxf(mx, __shfl_xor(mx, off));
    if (lane == 0) red[w] = mx;
    __syncthreads();
    mx = fmaxf(fmaxf(red[0], red[1]), fmaxf(red[2], red[3]));
    __syncthreads();

    float sum = 0.f;
    for (int i = tid; i < L; i += 256) { const float e = __expf(sc_s[i] - mx); sc_s[i] = e; sum += e; }
    #pragma unroll
    for (int off = 1; off < 64; off <<= 1) sum += __shfl_xor(sum, off);
    if (lane == 0) red[w] = sum;
    __syncthreads();
    sum = red[0] + red[1] + red[2] + red[3];
    const float inv = 1.f / sum;

    const int d = tid & 127, team = tid >> 7;
    const float* vdrow = vb_ + (size_t)(DOFF_ + b) * H_ + h * HD_;
    float acc = 0.f;
    for (int l = team; l < L; l += 2) {
        const float* src = (l == kvlen) ? vdrow
                                        : vc + (((size_t)b * LMAX_ + l) * NH_ + h) * HD_;
        acc += sc_s[l] * src[d];
    }
    if (team == 1) oacc[d] = acc;
    __syncthreads();
    if (team == 0) attn16[(size_t)(DOFF_ + b) * H_ + h * HD_ + d] = (__bf16)((acc + oacc[d]) * inv);
}

// ---------------------------------------------------------------- host launch
extern "C" void kernel_launch(void* const* d_in, const int* in_sizes, int n_in,
                              void* d_out, int out_size, void* d_ws, size_t ws_size,
                              hipStream_t stream)
{
    const float* hs     = (const float*)d_in[0];
    const float* wq     = (const float*)d_in[1];
    const float* wk     = (const float*)d_in[2];
    const float* wv     = (const float*)d_in[3];
    const float* wo     = (const float*)d_in[4];
    const float* la_q   = (const float*)d_in[5];
    const float* lb_q   = (const float*)d_in[6];
    const float* la_k   = (const float*)d_in[7];
    const float* lb_k   = (const float*)d_in[8];
    const float* la_v   = (const float*)d_in[9];
    const float* lb_v   = (const float*)d_in[10];
    const float* la_o   = (const float*)d_in[11];
    const float* lb_o   = (const float*)d_in[12];
    const float* kcache = (const float*)d_in[13];
    const float* vcache = (const float*)d_in[14];
    const int*   kvlen  = (const int*)d_in[15];
    float* out = (float*)d_out;

    float* qbuf    = (float*)d_ws;
    float* kbuf    = qbuf + (size_t)T_ * H_;
    float* vbuf    = kbuf + (size_t)T_ * H_;
    float* attnf   = vbuf + (size_t)T_ * H_;
    float* tmpbuf  = attnf + (size_t)T_ * H_;
    float* costab  = tmpbuf + (size_t)3 * T_ * RANK_;
    float* sintab  = costab + 1024 * 64;
    __bf16* hsb    = (__bf16*)(sintab + 1024 * 64);   // MPAD_ x H: hs bf16, later attn bf16
    __bf16* wT     = hsb + (size_t)MPAD_ * H_;        // 3 x H x H bf16

    __bf16* q16 = (__bf16*)attnf;
    __bf16* k16 = q16 + (size_t)T_ * H_;
    __bf16* vT  = wT + (size_t)H_ * H_;               // reuse wk^T region after QKV GEMM
    __bf16* attn16 = hsb;

    const int N8 = T_ * H_ / 8;

    rope_table_kernel<<<dim3(1024), dim3(64), 0, stream>>>(costab, sintab);
    convert_bf16_kernel<<<dim3(2048), dim3(256), 0, stream>>>(hs, hsb, N8);
    transpose_bf16_kernel<<<dim3(128, 128, 3), dim3(256), 0, stream>>>(
        wq, wk, wv, wT, wT + (size_t)H_ * H_, wT + (size_t)2 * H_ * H_);
    gemm_mfma8<<<dim3(21, 16, 3), dim3(512), 0, stream>>>(
        hsb, wT, wT + (size_t)H_ * H_, wT + (size_t)2 * H_ * H_, qbuf, kbuf, vbuf, T_);
    lora_tmp_kernel<<<dim3(T_, 3), dim3(256), 0, stream>>>(hs, la_q, la_k, la_v, tmpbuf);
    lora_rope_fused<<<dim3(T_), dim3(256), 0, stream>>>(qbuf, kbuf, vbuf, tmpbuf,
                                                        lb_q, lb_k, lb_v, kvlen,
                                                        costab, sintab, q16, k16);
    transpose_v_kernel<<<dim3(40, 32), dim3(256), 0, stream>>>(vbuf, vT);
    prefill_attn_mfma<<<dim3(40, 32), dim3(256), 0, stream>>>(q16, k16, vT, attn16);
    decode_attn_kernel<<<dim3(DEC_, NH_), dim3(256), 0, stream>>>(qbuf, kbuf, vbuf, kcache, vcache,
                                                                  kvlen, costab, sintab, attn16);
    transpose_bf16_kernel<<<dim3(128, 128, 1), dim3(256), 0, stream>>>(wo, wo, wo, wT, wT, wT);
    gemm_mfma8<<<dim3(21, 16, 1), dim3(512), 0, stream>>>(
        attn16, wT, wT, wT, out, out, out, T_);
    lora_tmp_bf16_kernel<<<dim3(T_), dim3(256), 0, stream>>>(attn16, la_o, tmpbuf);
    lora_add_kernel<<<dim3(T_, 16, 1), dim3(256), 0, stream>>>(tmpbuf, lb_o, lb_o, lb_o, out, out, out);
}

// Round 6
// 1199.708 us; speedup vs baseline: 1.0016x; 1.0016x over previous
//
#include <hip/hip_runtime.h>
#include <hip/hip_bf16.h>

// LlamaAttentionWithLora on MI355X — round 6.
// GEMM: (BM,BN)=(256,192), BK=64, QKV fused over N=12288 -> 704 blocks (91.7% grid eff),
// O-proj 242 blocks (94.5%). 24-MFMA phases, full-tile staging, 8-way XOR swizzle,
// bijective XCD swizzle. lora_tmp single-pass over hs.

#define H_    4096
#define NH_   32
#define HD_   128
#define T_    2592
#define DOFF_ 2560
#define DEC_  32
#define LMAX_ 512
#define RANK_ 16
#define MPAD_ 2816

__constant__ float SCALE_ = 0.08838834764831845f; // 128^-0.5

typedef __bf16 bf16x8 __attribute__((ext_vector_type(8)));
typedef __bf16 bf16x4 __attribute__((ext_vector_type(4)));
typedef float  f32x4  __attribute__((ext_vector_type(4)));

__device__ __forceinline__ void async_cp16(const __bf16* g, __bf16* l) {
    __builtin_amdgcn_global_load_lds(
        (const __attribute__((address_space(1))) void*)g,
        (__attribute__((address_space(3))) void*)l, 16, 0, 0);
}

// ---------------------------------------------------------------- f32 -> bf16 convert
__global__ __launch_bounds__(256)
void convert_bf16_kernel(const float* __restrict__ src, __bf16* __restrict__ dst, int n8)
{
    const int stride = gridDim.x * blockDim.x;
    for (int i = blockIdx.x * blockDim.x + threadIdx.x; i < n8; i += stride) {
        float4 a = ((const float4*)src)[i * 2];
        float4 b = ((const float4*)src)[i * 2 + 1];
        bf16x8 w;
        w[0] = (__bf16)a.x; w[1] = (__bf16)a.y; w[2] = (__bf16)a.z; w[3] = (__bf16)a.w;
        w[4] = (__bf16)b.x; w[5] = (__bf16)b.y; w[6] = (__bf16)b.z; w[7] = (__bf16)b.w;
        ((bf16x8*)dst)[i] = w;
    }
}

// ---------------------------------------------------------------- f32 [K][N] -> bf16 [N][K]
__global__ __launch_bounds__(256)
void transpose_bf16_kernel(const float* __restrict__ W0, const float* __restrict__ W1,
                           const float* __restrict__ W2,
                           __bf16* __restrict__ T0, __bf16* __restrict__ T1, __bf16* __restrict__ T2)
{
    const float* W = (blockIdx.z == 0) ? W0 : (blockIdx.z == 1 ? W1 : W2);
    __bf16* To     = (blockIdx.z == 0) ? T0 : (blockIdx.z == 1 ? T1 : T2);
    __shared__ float s[32][33];
    const int bx = blockIdx.x * 32;
    const int by = blockIdx.y * 32;
    const int r  = threadIdx.x >> 3;
    const int c4 = (threadIdx.x & 7) * 4;
    float4 v = *(const float4*)&W[(size_t)(by + r) * H_ + bx + c4];
    s[r][c4] = v.x; s[r][c4 + 1] = v.y; s[r][c4 + 2] = v.z; s[r][c4 + 3] = v.w;
    __syncthreads();
    bf16x4 o;
    o[0] = (__bf16)s[c4 + 0][r]; o[1] = (__bf16)s[c4 + 1][r];
    o[2] = (__bf16)s[c4 + 2][r]; o[3] = (__bf16)s[c4 + 3][r];
    *(bf16x4*)&To[(size_t)(bx + r) * H_ + by + c4] = o;
}

// ---------------------------------------------------------------- V transpose per head
__global__ __launch_bounds__(256)
void transpose_v_kernel(const float* __restrict__ v, __bf16* __restrict__ vT)
{
    __shared__ float s[64][129];
    const int tb = blockIdx.x;
    const int h  = blockIdx.y;
    const int tid = threadIdx.x;
    #pragma unroll
    for (int i = 0; i < 8; ++i) {
        const int idx = i * 256 + tid;
        const int row = idx >> 5;
        const int c4  = (idx & 31) * 4;
        *(float4*)&s[row][c4] = *(const float4*)&v[(size_t)(tb * 64 + row) * H_ + h * HD_ + c4];
    }
    __syncthreads();
    #pragma unroll
    for (int i = 0; i < 4; ++i) {
        const int idx = i * 256 + tid;
        const int d = idx >> 3;
        const int c = idx & 7;
        bf16x8 w;
        #pragma unroll
        for (int j = 0; j < 8; ++j) w[j] = (__bf16)s[c * 8 + j][d];
        *(bf16x8*)&vT[(size_t)(h * HD_ + d) * T_ + tb * 64 + c * 8] = w;
    }
}

// ---------------------------------------------------------------- GEMM (256x192, BK=64)
// C = A @ Bt^T. A: bf16 rm (rows padded). Bt: (Ntot-padded) x 4096 bf16 [n][k].
// Grid (NX=M-tiles, NY=N-tiles). Output col routed to C0/C1/C2 by col>>12, masked col<Ntot.
__global__ __launch_bounds__(512, 2)
void gemm_fused(const __bf16* __restrict__ A, const __bf16* __restrict__ Bt,
                float* __restrict__ C0, float* __restrict__ C1, float* __restrict__ C2,
                int M, int Ntot)
{
    const int NY = gridDim.y;
    const int total = gridDim.x * NY;
    // bijective XCD swizzle (m204), bx-major ordering for A-panel L2 locality
    const int bid = blockIdx.x * NY + blockIdx.y;
    const int q = total >> 3, r8 = total & 7;
    const int xcd = bid & 7, j = bid >> 3;
    const int swz = (xcd < r8 ? xcd * (q + 1) : r8 * (q + 1) + (xcd - r8) * q) + j;
    const int bm0 = (swz / NY) * 256;
    const int bn0 = (swz % NY) * 192;

    // [buf][row][8 phys chunks of 8 bf16]; phys p holds logical chunk p ^ (row&7)
    __shared__ __align__(16) __bf16 Asl[2][256 * 64];  // 2 x 32KB
    __shared__ __align__(16) __bf16 Bsl[2][192 * 64];  // 2 x 24KB

    const int tid = threadIdx.x, lane = tid & 63, wid = tid >> 6;
    const int wr = wid >> 2, wc = wid & 3;             // 2M x 4N waves, wave tile 128x48
    const int fr = lane & 15, fq = lane >> 4;

    // staging: instr i covers chunks ci = i*512 + tid; row = ci>>3, phys = ci&7
    int arow[4], aoff[4], brow[3], boff[3];
    #pragma unroll
    for (int i = 0; i < 4; ++i) {
        const int ci = i * 512 + tid;
        arow[i] = ci >> 3;
        aoff[i] = ((ci & 7) ^ (arow[i] & 7)) * 8;      // logical k-chunk in global
    }
    #pragma unroll
    for (int i = 0; i < 3; ++i) {
        const int ci = i * 512 + tid;
        brow[i] = ci >> 3;
        boff[i] = ((ci & 7) ^ (brow[i] & 7)) * 8;
    }
    const __bf16* Ab = A  + (size_t)bm0 * H_;
    const __bf16* Bb = Bt + (size_t)bn0 * H_;

    auto stage = [&](int buf, int kt1) {
        const int kb = kt1 * 64;
        #pragma unroll
        for (int i = 0; i < 4; ++i)
            async_cp16(Ab + (size_t)arow[i] * H_ + kb + aoff[i],
                       &Asl[buf][(i * 512 + wid * 64) * 8]);
        #pragma unroll
        for (int i = 0; i < 3; ++i)
            async_cp16(Bb + (size_t)brow[i] * H_ + kb + boff[i],
                       &Bsl[buf][(i * 512 + wid * 64) * 8]);
    };
    auto rdA = [&](int buf, int kh, int mi) -> bf16x8 {
        const int row = wr * 128 + mi * 16 + fr;
        const int kc  = kh * 4 + fq;
        return *(const bf16x8*)&Asl[buf][row * 64 + ((kc ^ (row & 7)) << 3)];
    };
    auto rdB = [&](int buf, int kh, int nj) -> bf16x8 {
        const int row = wc * 48 + nj * 16 + fr;
        const int kc  = kh * 4 + fq;
        return *(const bf16x8*)&Bsl[buf][row * 64 + ((kc ^ (row & 7)) << 3)];
    };

    f32x4 acc[8][3] = {};

    stage(0, 0);
    asm volatile("s_waitcnt vmcnt(0)");
    __builtin_amdgcn_sched_barrier(0);
    __builtin_amdgcn_s_barrier();

    const int NT = H_ / 64;
    for (int kt = 0; kt < NT; ++kt) {
        const int cur = kt & 1, nb = cur ^ 1;
        const bool pf = (kt + 1 < NT);
        bf16x8 af[8], bfr[3];

        // ---- phase 0 (kh0): issue next tile's 7 loads early
        #pragma unroll
        for (int mi = 0; mi < 8; ++mi) af[mi] = rdA(cur, 0, mi);
        #pragma unroll
        for (int nj = 0; nj < 3; ++nj) bfr[nj] = rdB(cur, 0, nj);
        if (pf) stage(nb, kt + 1);
        __builtin_amdgcn_s_barrier();
        asm volatile("s_waitcnt lgkmcnt(0)");
        __builtin_amdgcn_sched_barrier(0);
        __builtin_amdgcn_s_setprio(1);
        #pragma unroll
        for (int mi = 0; mi < 8; ++mi)
            #pragma unroll
            for (int nj = 0; nj < 3; ++nj)
                acc[mi][nj] = __builtin_amdgcn_mfma_f32_16x16x32_bf16(af[mi], bfr[nj], acc[mi][nj], 0, 0, 0);
        __builtin_amdgcn_s_setprio(0);
        __builtin_amdgcn_s_barrier();

        // ---- phase 1 (kh1): wait next tile's loads only at the end (~48 MFMA after issue)
        #pragma unroll
        for (int mi = 0; mi < 8; ++mi) af[mi] = rdA(cur, 1, mi);
        #pragma unroll
        for (int nj = 0; nj < 3; ++nj) bfr[nj] = rdB(cur, 1, nj);
        __builtin_amdgcn_s_barrier();
        asm volatile("s_waitcnt lgkmcnt(0)");
        __builtin_amdgcn_sched_barrier(0);
        __builtin_amdgcn_s_setprio(1);
        #pragma unroll
        for (int mi = 0; mi < 8; ++mi)
            #pragma unroll
            for (int nj = 0; nj < 3; ++nj)
                acc[mi][nj] = __builtin_amdgcn_mfma_f32_16x16x32_bf16(af[mi], bfr[nj], acc[mi][nj], 0, 0, 0);
        __builtin_amdgcn_s_setprio(0);
        asm volatile("s_waitcnt vmcnt(0)");
        __builtin_amdgcn_sched_barrier(0);
        __builtin_amdgcn_s_barrier();
    }

    // epilogue: fragment col base is 16-aligned -> whole fragment maps to one matrix
    #pragma unroll
    for (int mi = 0; mi < 8; ++mi)
        #pragma unroll
        for (int nj = 0; nj < 3; ++nj) {
            const int col = bn0 + wc * 48 + nj * 16 + fr;
            if (col < Ntot) {
                const int mat = col >> 12;
                float* C = (mat == 0) ? C0 : (mat == 1 ? C1 : C2);
                const int cc = col & 4095;
                #pragma unroll
                for (int rr = 0; rr < 4; ++rr) {
                    const int row = bm0 + wr * 128 + mi * 16 + fq * 4 + rr;
                    if (row < M) C[(size_t)row * H_ + cc] = acc[mi][nj][rr];
                }
            }
        }
}

// ---------------------------------------------------------------- LoRA stage 1 (f32 X, all 3 z in one pass)
__global__ __launch_bounds__(256)
void lora_tmp_kernel(const float* __restrict__ X,
                     const float* __restrict__ la0, const float* __restrict__ la1,
                     const float* __restrict__ la2, float* __restrict__ tmp)
{
    const int r = blockIdx.x;
    const int si = (r < 648) ? 0 : (r < 1296 ? 1 : (r < 1944 ? 2 : 3));
    const int c    = threadIdx.x & 15;
    const int part = threadIdx.x >> 4;
    const float* xr = X + (size_t)r * H_;
    const float* wa0 = la0 + (size_t)si * H_ * RANK_;
    const float* wa1 = la1 + (size_t)si * H_ * RANK_;
    const float* wa2 = la2 + (size_t)si * H_ * RANK_;
    float s0 = 0.f, s1 = 0.f, s2 = 0.f;
    const int h0 = part * 256;
    for (int h = h0; h < h0 + 256; ++h) {
        const float xv = xr[h];
        s0 += xv * wa0[(size_t)h * RANK_ + c];
        s1 += xv * wa1[(size_t)h * RANK_ + c];
        s2 += xv * wa2[(size_t)h * RANK_ + c];
    }
    __shared__ float red[3][16][17];
    red[0][part][c] = s0; red[1][part][c] = s1; red[2][part][c] = s2;
    __syncthreads();
    if (threadIdx.x < 48) {
        const int z = threadIdx.x >> 4, cc = threadIdx.x & 15;
        float t = 0.f;
        #pragma unroll
        for (int p = 0; p < 16; ++p) t += red[z][p][cc];
        tmp[((size_t)z * T_ + r) * RANK_ + cc] = t;
    }
}

// ---------------------------------------------------------------- LoRA stage 1 (bf16 X)
__global__ __launch_bounds__(256)
void lora_tmp_bf16_kernel(const __bf16* __restrict__ X,
                          const float* __restrict__ la, float* __restrict__ tmp)
{
    const int r = blockIdx.x;
    const int si = (r < 648) ? 0 : (r < 1296 ? 1 : (r < 1944 ? 2 : 3));
    const float* wa = la + (size_t)si * H_ * RANK_;
    const int c    = threadIdx.x & 15;
    const int part = threadIdx.x >> 4;
    const __bf16* xr = X + (size_t)r * H_;
    float s = 0.f;
    const int h0 = part * 256;
    for (int h = h0; h < h0 + 256; ++h) s += (float)xr[h] * wa[(size_t)h * RANK_ + c];
    __shared__ float red[16][17];
    red[part][c] = s;
    __syncthreads();
    if (threadIdx.x < 16) {
        float t = 0.f;
        #pragma unroll
        for (int p = 0; p < 16; ++p) t += red[p][threadIdx.x];
        tmp[(size_t)r * RANK_ + threadIdx.x] = t;
    }
}

// ---------------------------------------------------------------- LoRA stage 2 (O-proj)
__global__ __launch_bounds__(256)
void lora_add_kernel(const float* __restrict__ tmp,
                     const float* __restrict__ lb0, const float* __restrict__ lb1,
                     const float* __restrict__ lb2,
                     float* __restrict__ Y0, float* __restrict__ Y1, float* __restrict__ Y2)
{
    const int z = blockIdx.z;
    const float* lb = (z == 0) ? lb0 : (z == 1 ? lb1 : lb2);
    float* Y = (z == 0) ? Y0 : (z == 1 ? Y1 : Y2);
    const int r = blockIdx.x;
    const int n = blockIdx.y * 256 + threadIdx.x;
    const int si = (r < 648) ? 0 : (r < 1296 ? 1 : (r < 1944 ? 2 : 3));
    const float* wb = lb + (size_t)si * RANK_ * H_;
    __shared__ float tl[16];
    if (threadIdx.x < 16) tl[threadIdx.x] = tmp[((size_t)z * T_ + r) * RANK_ + threadIdx.x];
    __syncthreads();
    float s = 0.f;
    #pragma unroll
    for (int c = 0; c < 16; ++c) s += tl[c] * wb[(size_t)c * H_ + n];
    Y[(size_t)r * H_ + n] += s;
}

// ---------------------------------------------------------------- RoPE tables
__global__ void rope_table_kernel(float* __restrict__ cost, float* __restrict__ sint)
{
    const int p = blockIdx.x;
    const int i = threadIdx.x;
    const float inv = powf(10000.f, -(float)(2 * i) / (float)HD_);
    const float a = (float)p * inv;
    cost[p * 64 + i] = cosf(a);
    sint[p * 64 + i] = sinf(a);
}

// ---------------------------------------------------------------- fused: Y += lora, rope(q,k), bf16 emit
__global__ __launch_bounds__(256)
void lora_rope_fused(float* __restrict__ q, float* __restrict__ k, float* __restrict__ v,
                     const float* __restrict__ tmp,
                     const float* __restrict__ lbq, const float* __restrict__ lbk,
                     const float* __restrict__ lbv,
                     const int* __restrict__ kv_lens,
                     const float* __restrict__ cost, const float* __restrict__ sint,
                     __bf16* __restrict__ q16, __bf16* __restrict__ k16)
{
    const int r = blockIdx.x;
    const int si = (r < 648) ? 0 : (r < 1296 ? 1 : (r < 1944 ? 2 : 3));
    int pos; bool dok;
    if (r < DOFF_) {
        if      (r < 1024) pos = r;
        else if (r < 1536) pos = r - 1024;
        else if (r < 2304) pos = r - 1536;
        else               pos = r - 2304;
        dok = true;
    } else {
        pos = kv_lens[r - DOFF_];
        dok = false;
    }

    __shared__ float tq[16], tk[16], tv[16];
    const int tid = threadIdx.x;
    if (tid < 16)      tq[tid]      = tmp[(size_t)r * RANK_ + tid];
    else if (tid < 32) tk[tid - 16] = tmp[((size_t)T_ + r) * RANK_ + (tid - 16)];
    else if (tid < 48) tv[tid - 32] = tmp[((size_t)2 * T_ + r) * RANK_ + (tid - 32)];
    __syncthreads();

    const int h = tid >> 3, sub = tid & 7;
    const int i0 = sub * 8;
    const size_t b1 = (size_t)r * H_ + h * HD_ + i0;
    const size_t b2 = b1 + 64;
    const int n1 = h * HD_ + i0;

    float cs[8], sn[8];
    #pragma unroll
    for (int j = 0; j < 8; ++j) { cs[j] = cost[pos * 64 + i0 + j]; sn[j] = sint[pos * 64 + i0 + j]; }

    float y1[8], y2[8];
    // ---------------- Q
    {
        *(float4*)&y1[0] = *(const float4*)&q[b1]; *(float4*)&y1[4] = *(const float4*)&q[b1 + 4];
        *(float4*)&y2[0] = *(const float4*)&q[b2]; *(float4*)&y2[4] = *(const float4*)&q[b2 + 4];
        const float* wb = lbq + (size_t)si * RANK_ * H_;
        #pragma unroll
        for (int c = 0; c < 16; ++c) {
            const float tc = tq[c];
            const float* wr_ = wb + (size_t)c * H_ + n1;
            float4 w0 = *(const float4*)&wr_[0],  w1 = *(const float4*)&wr_[4];
            float4 w2 = *(const float4*)&wr_[64], w3 = *(const float4*)&wr_[68];
            y1[0] += tc * w0.x; y1[1] += tc * w0.y; y1[2] += tc * w0.z; y1[3] += tc * w0.w;
            y1[4] += tc * w1.x; y1[5] += tc * w1.y; y1[6] += tc * w1.z; y1[7] += tc * w1.w;
            y2[0] += tc * w2.x; y2[1] += tc * w2.y; y2[2] += tc * w2.z; y2[3] += tc * w2.w;
            y2[4] += tc * w3.x; y2[5] += tc * w3.y; y2[6] += tc * w3.z; y2[7] += tc * w3.w;
        }
        float z1[8], z2[8];
        bf16x8 o1, o2;
        #pragma unroll
        for (int j = 0; j < 8; ++j) {
            z1[j] = y1[j] * cs[j] - y2[j] * sn[j];
            z2[j] = y2[j] * cs[j] + y1[j] * sn[j];
            o1[j] = (__bf16)z1[j]; o2[j] = (__bf16)z2[j];
        }
        *(float4*)&q[b1] = *(float4*)&z1[0]; *(float4*)&q[b1 + 4] = *(float4*)&z1[4];
        *(float4*)&q[b2] = *(float4*)&z2[0]; *(float4*)&q[b2 + 4] = *(float4*)&z2[4];
        *(bf16x8*)&q16[b1] = o1; *(bf16x8*)&q16[b2] = o2;
    }
    // ---------------- K
    {
        *(float4*)&y1[0] = *(const float4*)&k[b1]; *(float4*)&y1[4] = *(const float4*)&k[b1 + 4];
        *(float4*)&y2[0] = *(const float4*)&k[b2]; *(float4*)&y2[4] = *(const float4*)&k[b2 + 4];
        const float* wb = lbk + (size_t)si * RANK_ * H_;
        #pragma unroll
        for (int c = 0; c < 16; ++c) {
            const float tc = tk[c];
            const float* wr_ = wb + (size_t)c * H_ + n1;
            float4 w0 = *(const float4*)&wr_[0],  w1 = *(const float4*)&wr_[4];
            float4 w2 = *(const float4*)&wr_[64], w3 = *(const float4*)&wr_[68];
            y1[0] += tc * w0.x; y1[1] += tc * w0.y; y1[2] += tc * w0.z; y1[3] += tc * w0.w;
            y1[4] += tc * w1.x; y1[5] += tc * w1.y; y1[6] += tc * w1.z; y1[7] += tc * w1.w;
            y2[0] += tc * w2.x; y2[1] += tc * w2.y; y2[2] += tc * w2.z; y2[3] += tc * w2.w;
            y2[4] += tc * w3.x; y2[5] += tc * w3.y; y2[6] += tc * w3.z; y2[7] += tc * w3.w;
        }
        float z1[8], z2[8];
        bf16x8 o1, o2;
        #pragma unroll
        for (int j = 0; j < 8; ++j) {
            if (dok) {
                z1[j] = y1[j] * cs[j] - y2[j] * sn[j];
                z2[j] = y2[j] * cs[j] + y1[j] * sn[j];
            } else {
                z1[j] = y1[j]; z2[j] = y2[j];
            }
            o1[j] = (__bf16)z1[j]; o2[j] = (__bf16)z2[j];
        }
        *(float4*)&k[b1] = *(float4*)&z1[0]; *(float4*)&k[b1 + 4] = *(float4*)&z1[4];
        *(float4*)&k[b2] = *(float4*)&z2[0]; *(float4*)&k[b2 + 4] = *(float4*)&z2[4];
        *(bf16x8*)&k16[b1] = o1; *(bf16x8*)&k16[b2] = o2;
    }
    // ---------------- V (no rope)
    {
        *(float4*)&y1[0] = *(const float4*)&v[b1]; *(float4*)&y1[4] = *(const float4*)&v[b1 + 4];
        *(float4*)&y2[0] = *(const float4*)&v[b2]; *(float4*)&y2[4] = *(const float4*)&v[b2 + 4];
        const float* wb = lbv + (size_t)si * RANK_ * H_;
        #pragma unroll
        for (int c = 0; c < 16; ++c) {
            const float tc = tv[c];
            const float* wr_ = wb + (size_t)c * H_ + n1;
            float4 w0 = *(const float4*)&wr_[0],  w1 = *(const float4*)&wr_[4];
            float4 w2 = *(const float4*)&wr_[64], w3 = *(const float4*)&wr_[68];
            y1[0] += tc * w0.x; y1[1] += tc * w0.y; y1[2] += tc * w0.z; y1[3] += tc * w0.w;
            y1[4] += tc * w1.x; y1[5] += tc * w1.y; y1[6] += tc * w1.z; y1[7] += tc * w1.w;
            y2[0] += tc * w2.x; y2[1] += tc * w2.y; y2[2] += tc * w2.z; y2[3] += tc * w2.w;
            y2[4] += tc * w3.x; y2[5] += tc * w3.y; y2[6] += tc * w3.z; y2[7] += tc * w3.w;
        }
        *(float4*)&v[b1] = *(float4*)&y1[0]; *(float4*)&v[b1 + 4] = *(float4*)&y1[4];
        *(float4*)&v[b2] = *(float4*)&y2[0]; *(float4*)&v[b2 + 4] = *(float4*)&y2[4];
    }
}

// ---------------------------------------------------------------- prefill attention (MFMA bf16, flash)
__global__ __launch_bounds__(256)
void prefill_attn_mfma(const __bf16* __restrict__ q16, const __bf16* __restrict__ k16,
                       const __bf16* __restrict__ vT, __bf16* __restrict__ attn16)
{
    const int qb = blockIdx.x;
    int soff, qoff;
    if      (qb < 16) { soff = 0;    qoff = qb * 64; }
    else if (qb < 24) { soff = 1024; qoff = (qb - 16) * 64; }
    else if (qb < 36) { soff = 1536; qoff = (qb - 24) * 64; }
    else              { soff = 2304; qoff = (qb - 36) * 64; }
    const int h = blockIdx.y;

    __shared__ __align__(16) __bf16 Kl[64 * 128];
    __shared__ __align__(16) __bf16 Vl[128 * 64];
    __shared__ __align__(16) __bf16 Pl[4][16 * 64];

    const int tid = threadIdx.x, lane = tid & 63, wid = tid >> 6;
    const int fr = lane & 15, fq = lane >> 4;

    const int grow0 = soff + qoff + wid * 16;
    bf16x8 qf[4];
    #pragma unroll
    for (int ks = 0; ks < 4; ++ks)
        qf[ks] = *(const bf16x8*)&q16[(size_t)(grow0 + fr) * H_ + h * HD_ + ks * 32 + fq * 8];

    float m[4], l[4];
    #pragma unroll
    for (int r = 0; r < 4; ++r) { m[r] = -1e30f; l[r] = 0.f; }
    f32x4 o[8] = {};

    const int ntiles = qoff / 64 + 1;
    for (int t = 0; t < ntiles; ++t) {
        const int kt = t * 64;
        #pragma unroll
        for (int i = 0; i < 4; ++i) {
            const int chunk = i * 256 + tid;
            const int row = chunk >> 4, c = chunk & 15;
            async_cp16(k16 + (size_t)(soff + kt + row) * H_ + h * HD_ + ((c ^ (row & 7)) * 8),
                       Kl + (size_t)(i * 256 + wid * 64) * 8);
        }
        #pragma unroll
        for (int i = 0; i < 4; ++i) {
            const int chunk = i * 256 + tid;
            const int row = chunk >> 3, c = chunk & 7;
            async_cp16(vT + (size_t)(h * HD_ + row) * T_ + soff + kt + ((c ^ (row & 7)) * 8),
                       Vl + (size_t)(i * 256 + wid * 64) * 8);
        }
        __syncthreads();

        f32x4 s[4] = {};
        #pragma unroll
        for (int sub = 0; sub < 4; ++sub)
            #pragma unroll
            for (int ks = 0; ks < 4; ++ks) {
                bf16x8 b = *(const bf16x8*)&Kl[(sub * 16 + fr) * 128 + (((ks * 4 + fq) ^ (fr & 7)) * 8)];
                s[sub] = __builtin_amdgcn_mfma_f32_16x16x32_bf16(qf[ks], b, s[sub], 0, 0, 0);
            }

        float p[4][4];
        #pragma unroll
        for (int sub = 0; sub < 4; ++sub)
            #pragma unroll
            for (int r = 0; r < 4; ++r) {
                const int qpos = qoff + wid * 16 + fq * 4 + r;
                const int kpos = kt + sub * 16 + fr;
                p[sub][r] = (kpos <= qpos) ? s[sub][r] * SCALE_ : -1e30f;
            }
        float fsc[4];
        #pragma unroll
        for (int r = 0; r < 4; ++r) {
            float tm = fmaxf(fmaxf(p[0][r], p[1][r]), fmaxf(p[2][r], p[3][r]));
            tm = fmaxf(tm, __shfl_xor(tm, 1));
            tm = fmaxf(tm, __shfl_xor(tm, 2));
            tm = fmaxf(tm, __shfl_xor(tm, 4));
            tm = fmaxf(tm, __shfl_xor(tm, 8));
            const float mn = fmaxf(m[r], tm);
            fsc[r] = __expf(m[r] - mn);
            m[r] = mn;
            float ls = 0.f;
            #pragma unroll
            for (int sub = 0; sub < 4; ++sub) {
                p[sub][r] = __expf(p[sub][r] - mn);
                ls += p[sub][r];
            }
            l[r] = l[r] * fsc[r] + ls;
        }
        #pragma unroll
        for (int c = 0; c < 8; ++c)
            #pragma unroll
            for (int r = 0; r < 4; ++r) o[c][r] *= fsc[r];

        #pragma unroll
        for (int sub = 0; sub < 4; ++sub)
            #pragma unroll
            for (int r = 0; r < 4; ++r) {
                const int qr = fq * 4 + r;
                Pl[wid][qr * 64 + ((sub * 16 + fr) ^ ((qr & 7) << 3))] = (__bf16)p[sub][r];
            }
        bf16x8 pa[2];
        #pragma unroll
        for (int a = 0; a < 2; ++a)
            pa[a] = *(const bf16x8*)&Pl[wid][fr * 64 + (((a * 4 + fq) ^ (fr & 7)) * 8)];

        #pragma unroll
        for (int a = 0; a < 2; ++a)
            #pragma unroll
            for (int c = 0; c < 8; ++c) {
                bf16x8 bv = *(const bf16x8*)&Vl[(c * 16 + fr) * 64 + (((a * 4 + fq) ^ (fr & 7)) * 8)];
                o[c] = __builtin_amdgcn_mfma_f32_16x16x32_bf16(pa[a], bv, o[c], 0, 0, 0);
            }
        __syncthreads();
    }

    float inv[4];
    #pragma unroll
    for (int r = 0; r < 4; ++r) {
        float ls = l[r];
        ls += __shfl_xor(ls, 1); ls += __shfl_xor(ls, 2);
        ls += __shfl_xor(ls, 4); ls += __shfl_xor(ls, 8);
        inv[r] = 1.f / ls;
    }
    #pragma unroll
    for (int c = 0; c < 8; ++c)
        #pragma unroll
        for (int r = 0; r < 4; ++r)
            attn16[(size_t)(grow0 + fq * 4 + r) * H_ + h * HD_ + c * 16 + fr] = (__bf16)(o[c][r] * inv[r]);
}

// ---------------------------------------------------------------- decode attention
__global__ __launch_bounds__(256)
void decode_attn_kernel(const float* __restrict__ qb_, const float* __restrict__ kb_,
                        const float* __restrict__ vb_, const float* __restrict__ kc,
                        const float* __restrict__ vc, const int* __restrict__ kv_lens,
                        const float* __restrict__ cost, const float* __restrict__ sint,
                        __bf16* __restrict__ attn16)
{
    const int b = blockIdx.x, h = blockIdx.y;
    const int kvlen = kv_lens[b];
    const int L = kvlen + 1;
    const int tid = threadIdx.x, lane = tid & 63, w = tid >> 6;

    __shared__ float sc_s[LMAX_];
    __shared__ float red[4];
    __shared__ float oacc[HD_];

    const float* qrow = qb_ + (size_t)(DOFF_ + b) * H_ + h * HD_;
    const float q1 = qrow[lane], q2 = qrow[lane + 64];
    const float* kdrow = kb_ + (size_t)(DOFF_ + b) * H_ + h * HD_;

    for (int l = w; l < L; l += 4) {
        const float* src = (l == kvlen) ? kdrow
                                        : kc + (((size_t)b * LMAX_ + l) * NH_ + h) * HD_;
        const float k1 = src[lane], k2 = src[lane + 64];
        const float c = cost[l * 64 + lane], s = sint[l * 64 + lane];
        float d = q1 * (k1 * c - k2 * s) + q2 * (k2 * c + k1 * s);
        #pragma unroll
        for (int off = 1; off < 64; off <<= 1) d += __shfl_xor(d, off);
        if (lane == 0) sc_s[l] = d * SCALE_;
    }
    __syncthreads();

    float mx = -1e30f;
    for (int i = tid; i < L; i += 256) mx = fmaxf(mx, sc_s[i]);
    #pragma unroll
    for (int off = 1; off < 64; off <<= 1) mx = fmaxf(mx, __shfl_xor(mx, off));
    if (lane == 0) red[w] = mx;
    __syncthreads();
    mx = fmaxf(fmaxf(red[0], red[1]), fmaxf(red[2], red[3]));
    __syncthreads();

    float sum = 0.f;
    for (int i = tid; i < L; i += 256) { const float e = __expf(sc_s[i] - mx); sc_s[i] = e; sum += e; }
    #pragma unroll
    for (int off = 1; off < 64; off <<= 1) sum += __shfl_xor(sum, off);
    if (lane == 0) red[w] = sum;
    __syncthreads();
    sum = red[0] + red[1] + red[2] + red[3];
    const float inv = 1.f / sum;

    const int d = tid & 127, team = tid >> 7;
    const float* vdrow = vb_ + (size_t)(DOFF_ + b) * H_ + h * HD_;
    float acc = 0.f;
    for (int l = team; l < L; l += 2) {
        const float* src = (l == kvlen) ? vdrow
                                        : vc + (((size_t)b * LMAX_ + l) * NH_ + h) * HD_;
        acc += sc_s[l] * src[d];
    }
    if (team == 1) oacc[d] = acc;
    __syncthreads();
    if (team == 0) attn16[(size_t)(DOFF_ + b) * H_ + h * HD_ + d] = (__bf16)((acc + oacc[d]) * inv);
}

// ---------------------------------------------------------------- host launch
extern "C" void kernel_launch(void* const* d_in, const int* in_sizes, int n_in,
                              void* d_out, int out_size, void* d_ws, size_t ws_size,
                              hipStream_t stream)
{
    const float* hs     = (const float*)d_in[0];
    const float* wq     = (const float*)d_in[1];
    const float* wk     = (const float*)d_in[2];
    const float* wv     = (const float*)d_in[3];
    const float* wo     = (const float*)d_in[4];
    const float* la_q   = (const float*)d_in[5];
    const float* lb_q   = (const float*)d_in[6];
    const float* la_k   = (const float*)d_in[7];
    const float* lb_k   = (const float*)d_in[8];
    const float* la_v   = (const float*)d_in[9];
    const float* lb_v   = (const float*)d_in[10];
    const float* la_o   = (const float*)d_in[11];
    const float* lb_o   = (const float*)d_in[12];
    const float* kcache = (const float*)d_in[13];
    const float* vcache = (const float*)d_in[14];
    const int*   kvlen  = (const int*)d_in[15];
    float* out = (float*)d_out;

    float* qbuf    = (float*)d_ws;
    float* kbuf    = qbuf + (size_t)T_ * H_;
    float* vbuf    = kbuf + (size_t)T_ * H_;
    float* attnf   = vbuf + (size_t)T_ * H_;
    float* tmpbuf  = attnf + (size_t)T_ * H_;
    float* costab  = tmpbuf + (size_t)3 * T_ * RANK_;
    float* sintab  = costab + 1024 * 64;
    __bf16* hsb    = (__bf16*)(sintab + 1024 * 64);   // MPAD_ x H bf16 (hs, later attn)
    __bf16* wT     = hsb + (size_t)MPAD_ * H_;        // 3 x H x H bf16 = 12288 x 4096

    __bf16* q16 = (__bf16*)attnf;
    __bf16* k16 = q16 + (size_t)T_ * H_;
    __bf16* vT  = wT + (size_t)H_ * H_;               // reuse wk^T slot after QKV GEMM
    __bf16* attn16 = hsb;

    const int N8 = T_ * H_ / 8;

    rope_table_kernel<<<dim3(1024), dim3(64), 0, stream>>>(costab, sintab);
    convert_bf16_kernel<<<dim3(2048), dim3(256), 0, stream>>>(hs, hsb, N8);
    transpose_bf16_kernel<<<dim3(128, 128, 3), dim3(256), 0, stream>>>(
        wq, wk, wv, wT, wT + (size_t)H_ * H_, wT + (size_t)2 * H_ * H_);
    gemm_fused<<<dim3(11, 64), dim3(512), 0, stream>>>(
        hsb, wT, qbuf, kbuf, vbuf, T_, 3 * H_);
    lora_tmp_kernel<<<dim3(T_), dim3(256), 0, stream>>>(hs, la_q, la_k, la_v, tmpbuf);
    lora_rope_fused<<<dim3(T_), dim3(256), 0, stream>>>(qbuf, kbuf, vbuf, tmpbuf,
                                                        lb_q, lb_k, lb_v, kvlen,
                                                        costab, sintab, q16, k16);
    transpose_v_kernel<<<dim3(40, 32), dim3(256), 0, stream>>>(vbuf, vT);
    prefill_attn_mfma<<<dim3(40, 32), dim3(256), 0, stream>>>(q16, k16, vT, attn16);
    decode_attn_kernel<<<dim3(DEC_, NH_), dim3(256), 0, stream>>>(qbuf, kbuf, vbuf, kcache, vcache,
                                                                  kvlen, costab, sintab, attn16);
    transpose_bf16_kernel<<<dim3(128, 128, 1), dim3(256), 0, stream>>>(wo, wo, wo, wT, wT, wT);
    gemm_fused<<<dim3(11, 22), dim3(512), 0, stream>>>(
        attn16, wT, out, out, out, T_, H_);
    lora_tmp_bf16_kernel<<<dim3(T_), dim3(256), 0, stream>>>(attn16, la_o, tmpbuf);
    lora_add_kernel<<<dim3(T_, 16, 1), dim3(256), 0, stream>>>(tmpbuf, lb_o, lb_o, lb_o, out, out, out);
}

// Round 7
// 1141.797 us; speedup vs baseline: 1.0524x; 1.0507x over previous
//
#include <hip/hip_runtime.h>
#include <hip/hip_bf16.h>

// LlamaAttentionWithLora on MI355X — round 7.
// QKV GEMM: BM=128,BN=256,BK=64, 3-buffer LDS ring, full-tile-ahead prefetch with
// counted vmcnt(6) (never drains in steady state), 1008 blocks (98.4% grid eff).
// O-proj keeps the round-6 (256x192) kernel (242 blocks = single round).

#define H_    4096
#define NH_   32
#define HD_   128
#define T_    2592
#define DOFF_ 2560
#define DEC_  32
#define LMAX_ 512
#define RANK_ 16
#define MPAD_ 2816

__constant__ float SCALE_ = 0.08838834764831845f; // 128^-0.5

typedef __bf16 bf16x8 __attribute__((ext_vector_type(8)));
typedef __bf16 bf16x4 __attribute__((ext_vector_type(4)));
typedef float  f32x4  __attribute__((ext_vector_type(4)));

__device__ __forceinline__ void async_cp16(const __bf16* g, __bf16* l) {
    __builtin_amdgcn_global_load_lds(
        (const __attribute__((address_space(1))) void*)g,
        (__attribute__((address_space(3))) void*)l, 16, 0, 0);
}

// ---------------------------------------------------------------- f32 -> bf16 convert
__global__ __launch_bounds__(256)
void convert_bf16_kernel(const float* __restrict__ src, __bf16* __restrict__ dst, int n8)
{
    const int stride = gridDim.x * blockDim.x;
    for (int i = blockIdx.x * blockDim.x + threadIdx.x; i < n8; i += stride) {
        float4 a = ((const float4*)src)[i * 2];
        float4 b = ((const float4*)src)[i * 2 + 1];
        bf16x8 w;
        w[0] = (__bf16)a.x; w[1] = (__bf16)a.y; w[2] = (__bf16)a.z; w[3] = (__bf16)a.w;
        w[4] = (__bf16)b.x; w[5] = (__bf16)b.y; w[6] = (__bf16)b.z; w[7] = (__bf16)b.w;
        ((bf16x8*)dst)[i] = w;
    }
}

// ---------------------------------------------------------------- f32 [K][N] -> bf16 [N][K]
__global__ __launch_bounds__(256)
void transpose_bf16_kernel(const float* __restrict__ W0, const float* __restrict__ W1,
                           const float* __restrict__ W2,
                           __bf16* __restrict__ T0, __bf16* __restrict__ T1, __bf16* __restrict__ T2)
{
    const float* W = (blockIdx.z == 0) ? W0 : (blockIdx.z == 1 ? W1 : W2);
    __bf16* To     = (blockIdx.z == 0) ? T0 : (blockIdx.z == 1 ? T1 : T2);
    __shared__ float s[32][33];
    const int bx = blockIdx.x * 32;
    const int by = blockIdx.y * 32;
    const int r  = threadIdx.x >> 3;
    const int c4 = (threadIdx.x & 7) * 4;
    float4 v = *(const float4*)&W[(size_t)(by + r) * H_ + bx + c4];
    s[r][c4] = v.x; s[r][c4 + 1] = v.y; s[r][c4 + 2] = v.z; s[r][c4 + 3] = v.w;
    __syncthreads();
    bf16x4 o;
    o[0] = (__bf16)s[c4 + 0][r]; o[1] = (__bf16)s[c4 + 1][r];
    o[2] = (__bf16)s[c4 + 2][r]; o[3] = (__bf16)s[c4 + 3][r];
    *(bf16x4*)&To[(size_t)(bx + r) * H_ + by + c4] = o;
}

// ---------------------------------------------------------------- V transpose per head
__global__ __launch_bounds__(256)
void transpose_v_kernel(const float* __restrict__ v, __bf16* __restrict__ vT)
{
    __shared__ float s[64][129];
    const int tb = blockIdx.x;
    const int h  = blockIdx.y;
    const int tid = threadIdx.x;
    #pragma unroll
    for (int i = 0; i < 8; ++i) {
        const int idx = i * 256 + tid;
        const int row = idx >> 5;
        const int c4  = (idx & 31) * 4;
        *(float4*)&s[row][c4] = *(const float4*)&v[(size_t)(tb * 64 + row) * H_ + h * HD_ + c4];
    }
    __syncthreads();
    #pragma unroll
    for (int i = 0; i < 4; ++i) {
        const int idx = i * 256 + tid;
        const int d = idx >> 3;
        const int c = idx & 7;
        bf16x8 w;
        #pragma unroll
        for (int j = 0; j < 8; ++j) w[j] = (__bf16)s[c * 8 + j][d];
        *(bf16x8*)&vT[(size_t)(h * HD_ + d) * T_ + tb * 64 + c * 8] = w;
    }
}

// ---------------------------------------------------------------- QKV GEMM (128x256, BK=64, 3-buf ring)
// C = A @ Bt^T, Bt is fused [wq^T; wk^T; wv^T] (12288 x 4096). Grid (21, 48).
__global__ __launch_bounds__(512, 2)
void gemm_qkv(const __bf16* __restrict__ A, const __bf16* __restrict__ Bt,
              float* __restrict__ C0, float* __restrict__ C1, float* __restrict__ C2, int M)
{
    // XCD swizzle: hw linear -> XCD-contiguous work, B-panel-major within XCD
    const int hw = blockIdx.y * 21 + blockIdx.x;
    const int work = (hw & 7) * 126 + (hw >> 3);     // 1008 = 8 * 126
    const int bm0 = (work % 21) * 128;
    const int bn0 = (work / 21) * 256;

    __shared__ __align__(16) __bf16 Asl[3][128 * 64];   // 3 x 16KB
    __shared__ __align__(16) __bf16 Bsl[3][256 * 64];   // 3 x 32KB

    const int tid = threadIdx.x, lane = tid & 63, wid = tid >> 6;
    const int wr = wid >> 2, wc = wid & 3;              // 2M x 4N waves, wave tile 64x64
    const int fr = lane & 15, fq = lane >> 4;

    // staging maps (chunk = 8 bf16 = 16B; phys chunk c holds logical c ^ (row&7))
    int arow[2], aoff[2], brow[4], boff[4];
    #pragma unroll
    for (int i = 0; i < 2; ++i) {
        const int ci = i * 512 + tid;
        arow[i] = ci >> 3;
        aoff[i] = ((ci & 7) ^ (arow[i] & 7)) * 8;
    }
    #pragma unroll
    for (int i = 0; i < 4; ++i) {
        const int ci = i * 512 + tid;
        brow[i] = ci >> 3;
        boff[i] = ((ci & 7) ^ (brow[i] & 7)) * 8;
    }
    const __bf16* Ab = A  + (size_t)bm0 * H_;
    const __bf16* Bb = Bt + (size_t)bn0 * H_;

    auto stageA = [&](int buf, int kt2) {               // 2 loads
        const int kb = kt2 * 64;
        #pragma unroll
        for (int i = 0; i < 2; ++i)
            async_cp16(Ab + (size_t)arow[i] * H_ + kb + aoff[i],
                       &Asl[buf][(i * 512 + wid * 64) * 8]);
    };
    auto stageB1 = [&](int buf, int kt2) {              // 1 load (B instr 0)
        async_cp16(Bb + (size_t)brow[0] * H_ + kt2 * 64 + boff[0],
                   &Bsl[buf][(wid * 64) * 8]);
    };
    auto stageB3 = [&](int buf, int kt2) {              // 3 loads (B instrs 1..3)
        const int kb = kt2 * 64;
        #pragma unroll
        for (int i = 1; i < 4; ++i)
            async_cp16(Bb + (size_t)brow[i] * H_ + kb + boff[i],
                       &Bsl[buf][(i * 512 + wid * 64) * 8]);
    };
    auto rdA = [&](int buf, int kh, int mi) -> bf16x8 {
        const int row = wr * 64 + mi * 16 + fr;
        const int pc  = (kh * 4 + fq) ^ (row & 7);
        return *(const bf16x8*)&Asl[buf][row * 64 + pc * 8];
    };
    auto rdB = [&](int buf, int kh, int nj) -> bf16x8 {
        const int row = wc * 64 + nj * 16 + fr;
        const int pc  = (kh * 4 + fq) ^ (row & 7);
        return *(const bf16x8*)&Bsl[buf][row * 64 + pc * 8];
    };

    f32x4 acc[4][4] = {};

    // prologue: tiles 0 and 1 (12 loads); wait tile 0 (oldest 6)
    stageA(0, 0); stageB1(0, 0); stageB3(0, 0);
    stageA(1, 1); stageB1(1, 1); stageB3(1, 1);
    asm volatile("s_waitcnt vmcnt(6)");
    __builtin_amdgcn_sched_barrier(0);
    __builtin_amdgcn_s_barrier();

    const int NT = H_ / 64;  // 64
    int cur = 0, nxt = 2;    // nxt = buffer for tile kt+2
    for (int kt = 0; kt < NT; ++kt) {
        const bool pf = (kt + 2 < NT);
        bf16x8 af[4], bfr[4];

        // ---- phase 0 (kh0)
        #pragma unroll
        for (int mi = 0; mi < 4; ++mi) af[mi] = rdA(cur, 0, mi);
        #pragma unroll
        for (int nj = 0; nj < 4; ++nj) bfr[nj] = rdB(cur, 0, nj);
        if (pf) { stageA(nxt, kt + 2); stageB1(nxt, kt + 2); }
        __builtin_amdgcn_s_barrier();
        asm volatile("s_waitcnt lgkmcnt(0)");
        __builtin_amdgcn_sched_barrier(0);
        __builtin_amdgcn_s_setprio(1);
        #pragma unroll
        for (int mi = 0; mi < 4; ++mi)
            #pragma unroll
            for (int nj = 0; nj < 4; ++nj)
                acc[mi][nj] = __builtin_amdgcn_mfma_f32_16x16x32_bf16(af[mi], bfr[nj], acc[mi][nj], 0, 0, 0);
        __builtin_amdgcn_s_setprio(0);
        __builtin_amdgcn_s_barrier();

        // ---- phase 1 (kh1)
        #pragma unroll
        for (int mi = 0; mi < 4; ++mi) af[mi] = rdA(cur, 1, mi);
        #pragma unroll
        for (int nj = 0; nj < 4; ++nj) bfr[nj] = rdB(cur, 1, nj);
        if (pf) stageB3(nxt, kt + 2);
        __builtin_amdgcn_s_barrier();
        asm volatile("s_waitcnt lgkmcnt(0)");
        __builtin_amdgcn_sched_barrier(0);
        __builtin_amdgcn_s_setprio(1);
        #pragma unroll
        for (int mi = 0; mi < 4; ++mi)
            #pragma unroll
            for (int nj = 0; nj < 4; ++nj)
                acc[mi][nj] = __builtin_amdgcn_mfma_f32_16x16x32_bf16(af[mi], bfr[nj], acc[mi][nj], 0, 0, 0);
        __builtin_amdgcn_s_setprio(0);
        // tile boundary: land tile kt+1 (issued a full tile ago -> ~free)
        if (pf)               asm volatile("s_waitcnt vmcnt(6)");
        else if (kt + 1 < NT) asm volatile("s_waitcnt vmcnt(0)");
        __builtin_amdgcn_sched_barrier(0);
        __builtin_amdgcn_s_barrier();

        cur = (cur == 2) ? 0 : cur + 1;
        nxt = (nxt == 2) ? 0 : nxt + 1;
    }

    // epilogue: C row = fq*4+r, col = fr per fragment; route by col>>12
    #pragma unroll
    for (int mi = 0; mi < 4; ++mi)
        #pragma unroll
        for (int nj = 0; nj < 4; ++nj) {
            const int col = bn0 + wc * 64 + nj * 16 + fr;
            const int mat = col >> 12;
            float* C = (mat == 0) ? C0 : (mat == 1 ? C1 : C2);
            const int cc = col & 4095;
            #pragma unroll
            for (int rr = 0; rr < 4; ++rr) {
                const int row = bm0 + mi * 16 + fq * 4 + rr + wr * 64;
                if (row < M) C[(size_t)row * H_ + cc] = acc[mi][nj][rr];
            }
        }
}

// ---------------------------------------------------------------- O-proj GEMM (256x192, BK=64) — round-6 kernel
__global__ __launch_bounds__(512, 2)
void gemm_fused(const __bf16* __restrict__ A, const __bf16* __restrict__ Bt,
                float* __restrict__ C0, float* __restrict__ C1, float* __restrict__ C2,
                int M, int Ntot)
{
    const int NY = gridDim.y;
    const int total = gridDim.x * NY;
    const int bid = blockIdx.x * NY + blockIdx.y;
    const int q = total >> 3, r8 = total & 7;
    const int xcd = bid & 7, j = bid >> 3;
    const int swz = (xcd < r8 ? xcd * (q + 1) : r8 * (q + 1) + (xcd - r8) * q) + j;
    const int bm0 = (swz / NY) * 256;
    const int bn0 = (swz % NY) * 192;

    __shared__ __align__(16) __bf16 Asl[2][256 * 64];
    __shared__ __align__(16) __bf16 Bsl[2][192 * 64];

    const int tid = threadIdx.x, lane = tid & 63, wid = tid >> 6;
    const int wr = wid >> 2, wc = wid & 3;
    const int fr = lane & 15, fq = lane >> 4;

    int arow[4], aoff[4], brow[3], boff[3];
    #pragma unroll
    for (int i = 0; i < 4; ++i) {
        const int ci = i * 512 + tid;
        arow[i] = ci >> 3;
        aoff[i] = ((ci & 7) ^ (arow[i] & 7)) * 8;
    }
    #pragma unroll
    for (int i = 0; i < 3; ++i) {
        const int ci = i * 512 + tid;
        brow[i] = ci >> 3;
        boff[i] = ((ci & 7) ^ (brow[i] & 7)) * 8;
    }
    const __bf16* Ab = A  + (size_t)bm0 * H_;
    const __bf16* Bb = Bt + (size_t)bn0 * H_;

    auto stage = [&](int buf, int kt1) {
        const int kb = kt1 * 64;
        #pragma unroll
        for (int i = 0; i < 4; ++i)
            async_cp16(Ab + (size_t)arow[i] * H_ + kb + aoff[i],
                       &Asl[buf][(i * 512 + wid * 64) * 8]);
        #pragma unroll
        for (int i = 0; i < 3; ++i)
            async_cp16(Bb + (size_t)brow[i] * H_ + kb + boff[i],
                       &Bsl[buf][(i * 512 + wid * 64) * 8]);
    };
    auto rdA = [&](int buf, int kh, int mi) -> bf16x8 {
        const int row = wr * 128 + mi * 16 + fr;
        const int kc  = kh * 4 + fq;
        return *(const bf16x8*)&Asl[buf][row * 64 + ((kc ^ (row & 7)) << 3)];
    };
    auto rdB = [&](int buf, int kh, int nj) -> bf16x8 {
        const int row = wc * 48 + nj * 16 + fr;
        const int kc  = kh * 4 + fq;
        return *(const bf16x8*)&Bsl[buf][row * 64 + ((kc ^ (row & 7)) << 3)];
    };

    f32x4 acc[8][3] = {};

    stage(0, 0);
    asm volatile("s_waitcnt vmcnt(0)");
    __builtin_amdgcn_sched_barrier(0);
    __builtin_amdgcn_s_barrier();

    const int NT = H_ / 64;
    for (int kt = 0; kt < NT; ++kt) {
        const int cur = kt & 1, nb = cur ^ 1;
        const bool pf = (kt + 1 < NT);
        bf16x8 af[8], bfr[3];

        #pragma unroll
        for (int mi = 0; mi < 8; ++mi) af[mi] = rdA(cur, 0, mi);
        #pragma unroll
        for (int nj = 0; nj < 3; ++nj) bfr[nj] = rdB(cur, 0, nj);
        if (pf) stage(nb, kt + 1);
        __builtin_amdgcn_s_barrier();
        asm volatile("s_waitcnt lgkmcnt(0)");
        __builtin_amdgcn_sched_barrier(0);
        __builtin_amdgcn_s_setprio(1);
        #pragma unroll
        for (int mi = 0; mi < 8; ++mi)
            #pragma unroll
            for (int nj = 0; nj < 3; ++nj)
                acc[mi][nj] = __builtin_amdgcn_mfma_f32_16x16x32_bf16(af[mi], bfr[nj], acc[mi][nj], 0, 0, 0);
        __builtin_amdgcn_s_setprio(0);
        __builtin_amdgcn_s_barrier();

        #pragma unroll
        for (int mi = 0; mi < 8; ++mi) af[mi] = rdA(cur, 1, mi);
        #pragma unroll
        for (int nj = 0; nj < 3; ++nj) bfr[nj] = rdB(cur, 1, nj);
        __builtin_amdgcn_s_barrier();
        asm volatile("s_waitcnt lgkmcnt(0)");
        __builtin_amdgcn_sched_barrier(0);
        __builtin_amdgcn_s_setprio(1);
        #pragma unroll
        for (int mi = 0; mi < 8; ++mi)
            #pragma unroll
            for (int nj = 0; nj < 3; ++nj)
                acc[mi][nj] = __builtin_amdgcn_mfma_f32_16x16x32_bf16(af[mi], bfr[nj], acc[mi][nj], 0, 0, 0);
        __builtin_amdgcn_s_setprio(0);
        asm volatile("s_waitcnt vmcnt(0)");
        __builtin_amdgcn_sched_barrier(0);
        __builtin_amdgcn_s_barrier();
    }

    #pragma unroll
    for (int mi = 0; mi < 8; ++mi)
        #pragma unroll
        for (int nj = 0; nj < 3; ++nj) {
            const int col = bn0 + wc * 48 + nj * 16 + fr;
            if (col < Ntot) {
                const int mat = col >> 12;
                float* C = (mat == 0) ? C0 : (mat == 1 ? C1 : C2);
                const int cc = col & 4095;
                #pragma unroll
                for (int rr = 0; rr < 4; ++rr) {
                    const int row = bm0 + wr * 128 + mi * 16 + fq * 4 + rr;
                    if (row < M) C[(size_t)row * H_ + cc] = acc[mi][nj][rr];
                }
            }
        }
}

// ---------------------------------------------------------------- LoRA stage 1 (f32 X, all 3 z)
__global__ __launch_bounds__(256)
void lora_tmp_kernel(const float* __restrict__ X,
                     const float* __restrict__ la0, const float* __restrict__ la1,
                     const float* __restrict__ la2, float* __restrict__ tmp)
{
    const int r = blockIdx.x;
    const int si = (r < 648) ? 0 : (r < 1296 ? 1 : (r < 1944 ? 2 : 3));
    const int c    = threadIdx.x & 15;
    const int part = threadIdx.x >> 4;
    const float* xr = X + (size_t)r * H_;
    const float* wa0 = la0 + (size_t)si * H_ * RANK_;
    const float* wa1 = la1 + (size_t)si * H_ * RANK_;
    const float* wa2 = la2 + (size_t)si * H_ * RANK_;
    float s0 = 0.f, s1 = 0.f, s2 = 0.f;
    const int h0 = part * 256;
    for (int h = h0; h < h0 + 256; ++h) {
        const float xv = xr[h];
        s0 += xv * wa0[(size_t)h * RANK_ + c];
        s1 += xv * wa1[(size_t)h * RANK_ + c];
        s2 += xv * wa2[(size_t)h * RANK_ + c];
    }
    __shared__ float red[3][16][17];
    red[0][part][c] = s0; red[1][part][c] = s1; red[2][part][c] = s2;
    __syncthreads();
    if (threadIdx.x < 48) {
        const int z = threadIdx.x >> 4, cc = threadIdx.x & 15;
        float t = 0.f;
        #pragma unroll
        for (int p = 0; p < 16; ++p) t += red[z][p][cc];
        tmp[((size_t)z * T_ + r) * RANK_ + cc] = t;
    }
}

// ---------------------------------------------------------------- LoRA stage 1 (bf16 X)
__global__ __launch_bounds__(256)
void lora_tmp_bf16_kernel(const __bf16* __restrict__ X,
                          const float* __restrict__ la, float* __restrict__ tmp)
{
    const int r = blockIdx.x;
    const int si = (r < 648) ? 0 : (r < 1296 ? 1 : (r < 1944 ? 2 : 3));
    const float* wa = la + (size_t)si * H_ * RANK_;
    const int c    = threadIdx.x & 15;
    const int part = threadIdx.x >> 4;
    const __bf16* xr = X + (size_t)r * H_;
    float s = 0.f;
    const int h0 = part * 256;
    for (int h = h0; h < h0 + 256; ++h) s += (float)xr[h] * wa[(size_t)h * RANK_ + c];
    __shared__ float red[16][17];
    red[part][c] = s;
    __syncthreads();
    if (threadIdx.x < 16) {
        float t = 0.f;
        #pragma unroll
        for (int p = 0; p < 16; ++p) t += red[p][threadIdx.x];
        tmp[(size_t)r * RANK_ + threadIdx.x] = t;
    }
}

// ---------------------------------------------------------------- LoRA stage 2 (O-proj)
__global__ __launch_bounds__(256)
void lora_add_kernel(const float* __restrict__ tmp,
                     const float* __restrict__ lb0, const float* __restrict__ lb1,
                     const float* __restrict__ lb2,
                     float* __restrict__ Y0, float* __restrict__ Y1, float* __restrict__ Y2)
{
    const int z = blockIdx.z;
    const float* lb = (z == 0) ? lb0 : (z == 1 ? lb1 : lb2);
    float* Y = (z == 0) ? Y0 : (z == 1 ? Y1 : Y2);
    const int r = blockIdx.x;
    const int n = blockIdx.y * 256 + threadIdx.x;
    const int si = (r < 648) ? 0 : (r < 1296 ? 1 : (r < 1944 ? 2 : 3));
    const float* wb = lb + (size_t)si * RANK_ * H_;
    __shared__ float tl[16];
    if (threadIdx.x < 16) tl[threadIdx.x] = tmp[((size_t)z * T_ + r) * RANK_ + threadIdx.x];
    __syncthreads();
    float s = 0.f;
    #pragma unroll
    for (int c = 0; c < 16; ++c) s += tl[c] * wb[(size_t)c * H_ + n];
    Y[(size_t)r * H_ + n] += s;
}

// ---------------------------------------------------------------- RoPE tables
__global__ void rope_table_kernel(float* __restrict__ cost, float* __restrict__ sint)
{
    const int p = blockIdx.x;
    const int i = threadIdx.x;
    const float inv = powf(10000.f, -(float)(2 * i) / (float)HD_);
    const float a = (float)p * inv;
    cost[p * 64 + i] = cosf(a);
    sint[p * 64 + i] = sinf(a);
}

// ---------------------------------------------------------------- fused: Y += lora, rope(q,k), bf16 emit
__global__ __launch_bounds__(256)
void lora_rope_fused(float* __restrict__ q, float* __restrict__ k, float* __restrict__ v,
                     const float* __restrict__ tmp,
                     const float* __restrict__ lbq, const float* __restrict__ lbk,
                     const float* __restrict__ lbv,
                     const int* __restrict__ kv_lens,
                     const float* __restrict__ cost, const float* __restrict__ sint,
                     __bf16* __restrict__ q16, __bf16* __restrict__ k16)
{
    const int r = blockIdx.x;
    const int si = (r < 648) ? 0 : (r < 1296 ? 1 : (r < 1944 ? 2 : 3));
    int pos; bool dok;
    if (r < DOFF_) {
        if      (r < 1024) pos = r;
        else if (r < 1536) pos = r - 1024;
        else if (r < 2304) pos = r - 1536;
        else               pos = r - 2304;
        dok = true;
    } else {
        pos = kv_lens[r - DOFF_];
        dok = false;
    }

    __shared__ float tq[16], tk[16], tv[16];
    const int tid = threadIdx.x;
    if (tid < 16)      tq[tid]      = tmp[(size_t)r * RANK_ + tid];
    else if (tid < 32) tk[tid - 16] = tmp[((size_t)T_ + r) * RANK_ + (tid - 16)];
    else if (tid < 48) tv[tid - 32] = tmp[((size_t)2 * T_ + r) * RANK_ + (tid - 32)];
    __syncthreads();

    const int h = tid >> 3, sub = tid & 7;
    const int i0 = sub * 8;
    const size_t b1 = (size_t)r * H_ + h * HD_ + i0;
    const size_t b2 = b1 + 64;
    const int n1 = h * HD_ + i0;

    float cs[8], sn[8];
    #pragma unroll
    for (int j = 0; j < 8; ++j) { cs[j] = cost[pos * 64 + i0 + j]; sn[j] = sint[pos * 64 + i0 + j]; }

    float y1[8], y2[8];
    // ---------------- Q
    {
        *(float4*)&y1[0] = *(const float4*)&q[b1]; *(float4*)&y1[4] = *(const float4*)&q[b1 + 4];
        *(float4*)&y2[0] = *(const float4*)&q[b2]; *(float4*)&y2[4] = *(const float4*)&q[b2 + 4];
        const float* wb = lbq + (size_t)si * RANK_ * H_;
        #pragma unroll
        for (int c = 0; c < 16; ++c) {
            const float tc = tq[c];
            const float* wr_ = wb + (size_t)c * H_ + n1;
            float4 w0 = *(const float4*)&wr_[0],  w1 = *(const float4*)&wr_[4];
            float4 w2 = *(const float4*)&wr_[64], w3 = *(const float4*)&wr_[68];
            y1[0] += tc * w0.x; y1[1] += tc * w0.y; y1[2] += tc * w0.z; y1[3] += tc * w0.w;
            y1[4] += tc * w1.x; y1[5] += tc * w1.y; y1[6] += tc * w1.z; y1[7] += tc * w1.w;
            y2[0] += tc * w2.x; y2[1] += tc * w2.y; y2[2] += tc * w2.z; y2[3] += tc * w2.w;
            y2[4] += tc * w3.x; y2[5] += tc * w3.y; y2[6] += tc * w3.z; y2[7] += tc * w3.w;
        }
        float z1[8], z2[8];
        bf16x8 o1, o2;
        #pragma unroll
        for (int j = 0; j < 8; ++j) {
            z1[j] = y1[j] * cs[j] - y2[j] * sn[j];
            z2[j] = y2[j] * cs[j] + y1[j] * sn[j];
            o1[j] = (__bf16)z1[j]; o2[j] = (__bf16)z2[j];
        }
        *(float4*)&q[b1] = *(float4*)&z1[0]; *(float4*)&q[b1 + 4] = *(float4*)&z1[4];
        *(float4*)&q[b2] = *(float4*)&z2[0]; *(float4*)&q[b2 + 4] = *(float4*)&z2[4];
        *(bf16x8*)&q16[b1] = o1; *(bf16x8*)&q16[b2] = o2;
    }
    // ---------------- K
    {
        *(float4*)&y1[0] = *(const float4*)&k[b1]; *(float4*)&y1[4] = *(const float4*)&k[b1 + 4];
        *(float4*)&y2[0] = *(const float4*)&k[b2]; *(float4*)&y2[4] = *(const float4*)&k[b2 + 4];
        const float* wb = lbk + (size_t)si * RANK_ * H_;
        #pragma unroll
        for (int c = 0; c < 16; ++c) {
            const float tc = tk[c];
            const float* wr_ = wb + (size_t)c * H_ + n1;
            float4 w0 = *(const float4*)&wr_[0],  w1 = *(const float4*)&wr_[4];
            float4 w2 = *(const float4*)&wr_[64], w3 = *(const float4*)&wr_[68];
            y1[0] += tc * w0.x; y1[1] += tc * w0.y; y1[2] += tc * w0.z; y1[3] += tc * w0.w;
            y1[4] += tc * w1.x; y1[5] += tc * w1.y; y1[6] += tc * w1.z; y1[7] += tc * w1.w;
            y2[0] += tc * w2.x; y2[1] += tc * w2.y; y2[2] += tc * w2.z; y2[3] += tc * w2.w;
            y2[4] += tc * w3.x; y2[5] += tc * w3.y; y2[6] += tc * w3.z; y2[7] += tc * w3.w;
        }
        float z1[8], z2[8];
        bf16x8 o1, o2;
        #pragma unroll
        for (int j = 0; j < 8; ++j) {
            if (dok) {
                z1[j] = y1[j] * cs[j] - y2[j] * sn[j];
                z2[j] = y2[j] * cs[j] + y1[j] * sn[j];
            } else {
                z1[j] = y1[j]; z2[j] = y2[j];
            }
            o1[j] = (__bf16)z1[j]; o2[j] = (__bf16)z2[j];
        }
        *(float4*)&k[b1] = *(float4*)&z1[0]; *(float4*)&k[b1 + 4] = *(float4*)&z1[4];
        *(float4*)&k[b2] = *(float4*)&z2[0]; *(float4*)&k[b2 + 4] = *(float4*)&z2[4];
        *(bf16x8*)&k16[b1] = o1; *(bf16x8*)&k16[b2] = o2;
    }
    // ---------------- V (no rope)
    {
        *(float4*)&y1[0] = *(const float4*)&v[b1]; *(float4*)&y1[4] = *(const float4*)&v[b1 + 4];
        *(float4*)&y2[0] = *(const float4*)&v[b2]; *(float4*)&y2[4] = *(const float4*)&v[b2 + 4];
        const float* wb = lbv + (size_t)si * RANK_ * H_;
        #pragma unroll
        for (int c = 0; c < 16; ++c) {
            const float tc = tv[c];
            const float* wr_ = wb + (size_t)c * H_ + n1;
            float4 w0 = *(const float4*)&wr_[0],  w1 = *(const float4*)&wr_[4];
            float4 w2 = *(const float4*)&wr_[64], w3 = *(const float4*)&wr_[68];
            y1[0] += tc * w0.x; y1[1] += tc * w0.y; y1[2] += tc * w0.z; y1[3] += tc * w0.w;
            y1[4] += tc * w1.x; y1[5] += tc * w1.y; y1[6] += tc * w1.z; y1[7] += tc * w1.w;
            y2[0] += tc * w2.x; y2[1] += tc * w2.y; y2[2] += tc * w2.z; y2[3] += tc * w2.w;
            y2[4] += tc * w3.x; y2[5] += tc * w3.y; y2[6] += tc * w3.z; y2[7] += tc * w3.w;
        }
        *(float4*)&v[b1] = *(float4*)&y1[0]; *(float4*)&v[b1 + 4] = *(float4*)&y1[4];
        *(float4*)&v[b2] = *(float4*)&y2[0]; *(float4*)&v[b2 + 4] = *(float4*)&y2[4];
    }
}

// ---------------------------------------------------------------- prefill attention (MFMA bf16, flash)
__global__ __launch_bounds__(256)
void prefill_attn_mfma(const __bf16* __restrict__ q16, const __bf16* __restrict__ k16,
                       const __bf16* __restrict__ vT, __bf16* __restrict__ attn16)
{
    const int qb = blockIdx.x;
    int soff, qoff;
    if      (qb < 16) { soff = 0;    qoff = qb * 64; }
    else if (qb < 24) { soff = 1024; qoff = (qb - 16) * 64; }
    else if (qb < 36) { soff = 1536; qoff = (qb - 24) * 64; }
    else              { soff = 2304; qoff = (qb - 36) * 64; }
    const int h = blockIdx.y;

    __shared__ __align__(16) __bf16 Kl[64 * 128];
    __shared__ __align__(16) __bf16 Vl[128 * 64];
    __shared__ __align__(16) __bf16 Pl[4][16 * 64];

    const int tid = threadIdx.x, lane = tid & 63, wid = tid >> 6;
    const int fr = lane & 15, fq = lane >> 4;

    const int grow0 = soff + qoff + wid * 16;
    bf16x8 qf[4];
    #pragma unroll
    for (int ks = 0; ks < 4; ++ks)
        qf[ks] = *(const bf16x8*)&q16[(size_t)(grow0 + fr) * H_ + h * HD_ + ks * 32 + fq * 8];

    float m[4], l[4];
    #pragma unroll
    for (int r = 0; r < 4; ++r) { m[r] = -1e30f; l[r] = 0.f; }
    f32x4 o[8] = {};

    const int ntiles = qoff / 64 + 1;
    for (int t = 0; t < ntiles; ++t) {
        const int kt = t * 64;
        #pragma unroll
        for (int i = 0; i < 4; ++i) {
            const int chunk = i * 256 + tid;
            const int row = chunk >> 4, c = chunk & 15;
            async_cp16(k16 + (size_t)(soff + kt + row) * H_ + h * HD_ + ((c ^ (row & 7)) * 8),
                       Kl + (size_t)(i * 256 + wid * 64) * 8);
        }
        #pragma unroll
        for (int i = 0; i < 4; ++i) {
            const int chunk = i * 256 + tid;
            const int row = chunk >> 3, c = chunk & 7;
            async_cp16(vT + (size_t)(h * HD_ + row) * T_ + soff + kt + ((c ^ (row & 7)) * 8),
                       Vl + (size_t)(i * 256 + wid * 64) * 8);
        }
        __syncthreads();

        f32x4 s[4] = {};
        #pragma unroll
        for (int sub = 0; sub < 4; ++sub)
            #pragma unroll
            for (int ks = 0; ks < 4; ++ks) {
                bf16x8 b = *(const bf16x8*)&Kl[(sub * 16 + fr) * 128 + (((ks * 4 + fq) ^ (fr & 7)) * 8)];
                s[sub] = __builtin_amdgcn_mfma_f32_16x16x32_bf16(qf[ks], b, s[sub], 0, 0, 0);
            }

        float p[4][4];
        #pragma unroll
        for (int sub = 0; sub < 4; ++sub)
            #pragma unroll
            for (int r = 0; r < 4; ++r) {
                const int qpos = qoff + wid * 16 + fq * 4 + r;
                const int kpos = kt + sub * 16 + fr;
                p[sub][r] = (kpos <= qpos) ? s[sub][r] * SCALE_ : -1e30f;
            }
        float fsc[4];
        #pragma unroll
        for (int r = 0; r < 4; ++r) {
            float tm = fmaxf(fmaxf(p[0][r], p[1][r]), fmaxf(p[2][r], p[3][r]));
            tm = fmaxf(tm, __shfl_xor(tm, 1));
            tm = fmaxf(tm, __shfl_xor(tm, 2));
            tm = fmaxf(tm, __shfl_xor(tm, 4));
            tm = fmaxf(tm, __shfl_xor(tm, 8));
            const float mn = fmaxf(m[r], tm);
            fsc[r] = __expf(m[r] - mn);
            m[r] = mn;
            float ls = 0.f;
            #pragma unroll
            for (int sub = 0; sub < 4; ++sub) {
                p[sub][r] = __expf(p[sub][r] - mn);
                ls += p[sub][r];
            }
            l[r] = l[r] * fsc[r] + ls;
        }
        #pragma unroll
        for (int c = 0; c < 8; ++c)
            #pragma unroll
            for (int r = 0; r < 4; ++r) o[c][r] *= fsc[r];

        #pragma unroll
        for (int sub = 0; sub < 4; ++sub)
            #pragma unroll
            for (int r = 0; r < 4; ++r) {
                const int qr = fq * 4 + r;
                Pl[wid][qr * 64 + ((sub * 16 + fr) ^ ((qr & 7) << 3))] = (__bf16)p[sub][r];
            }
        bf16x8 pa[2];
        #pragma unroll
        for (int a = 0; a < 2; ++a)
            pa[a] = *(const bf16x8*)&Pl[wid][fr * 64 + (((a * 4 + fq) ^ (fr & 7)) * 8)];

        #pragma unroll
        for (int a = 0; a < 2; ++a)
            #pragma unroll
            for (int c = 0; c < 8; ++c) {
                bf16x8 bv = *(const bf16x8*)&Vl[(c * 16 + fr) * 64 + (((a * 4 + fq) ^ (fr & 7)) * 8)];
                o[c] = __builtin_amdgcn_mfma_f32_16x16x32_bf16(pa[a], bv, o[c], 0, 0, 0);
            }
        __syncthreads();
    }

    float inv[4];
    #pragma unroll
    for (int r = 0; r < 4; ++r) {
        float ls = l[r];
        ls += __shfl_xor(ls, 1); ls += __shfl_xor(ls, 2);
        ls += __shfl_xor(ls, 4); ls += __shfl_xor(ls, 8);
        inv[r] = 1.f / ls;
    }
    #pragma unroll
    for (int c = 0; c < 8; ++c)
        #pragma unroll
        for (int r = 0; r < 4; ++r)
            attn16[(size_t)(grow0 + fq * 4 + r) * H_ + h * HD_ + c * 16 + fr] = (__bf16)(o[c][r] * inv[r]);
}

// ---------------------------------------------------------------- decode attention
__global__ __launch_bounds__(256)
void decode_attn_kernel(const float* __restrict__ qb_, const float* __restrict__ kb_,
                        const float* __restrict__ vb_, const float* __restrict__ kc,
                        const float* __restrict__ vc, const int* __restrict__ kv_lens,
                        const float* __restrict__ cost, const float* __restrict__ sint,
                        __bf16* __restrict__ attn16)
{
    const int b = blockIdx.x, h = blockIdx.y;
    const int kvlen = kv_lens[b];
    const int L = kvlen + 1;
    const int tid = threadIdx.x, lane = tid & 63, w = tid >> 6;

    __shared__ float sc_s[LMAX_];
    __shared__ float red[4];
    __shared__ float oacc[HD_];

    const float* qrow = qb_ + (size_t)(DOFF_ + b) * H_ + h * HD_;
    const float q1 = qrow[lane], q2 = qrow[lane + 64];
    const float* kdrow = kb_ + (size_t)(DOFF_ + b) * H_ + h * HD_;

    for (int l = w; l < L; l += 4) {
        const float* src = (l == kvlen) ? kdrow
                                        : kc + (((size_t)b * LMAX_ + l) * NH_ + h) * HD_;
        const float k1 = src[lane], k2 = src[lane + 64];
        const float c = cost[l * 64 + lane], s = sint[l * 64 + lane];
        float d = q1 * (k1 * c - k2 * s) + q2 * (k2 * c + k1 * s);
        #pragma unroll
        for (int off = 1; off < 64; off <<= 1) d += __shfl_xor(d, off);
        if (lane == 0) sc_s[l] = d * SCALE_;
    }
    __syncthreads();

    float mx = -1e30f;
    for (int i = tid; i < L; i += 256) mx = fmaxf(mx, sc_s[i]);
    #pragma unroll
    for (int off = 1; off < 64; off <<= 1) mx = fmaxf(mx, __shfl_xor(mx, off));
    if (lane == 0) red[w] = mx;
    __syncthreads();
    mx = fmaxf(fmaxf(red[0], red[1]), fmaxf(red[2], red[3]));
    __syncthreads();

    float sum = 0.f;
    for (int i = tid; i < L; i += 256) { const float e = __expf(sc_s[i] - mx); sc_s[i] = e; sum += e; }
    #pragma unroll
    for (int off = 1; off < 64; off <<= 1) sum += __shfl_xor(sum, off);
    if (lane == 0) red[w] = sum;
    __syncthreads();
    sum = red[0] + red[1] + red[2] + red[3];
    const float inv = 1.f / sum;

    const int d = tid & 127, team = tid >> 7;
    const float* vdrow = vb_ + (size_t)(DOFF_ + b) * H_ + h * HD_;
    float acc = 0.f;
    for (int l = team; l < L; l += 2) {
        const float* src = (l == kvlen) ? vdrow
                                        : vc + (((size_t)b * LMAX_ + l) * NH_ + h) * HD_;
        acc += sc_s[l] * src[d];
    }
    if (team == 1) oacc[d] = acc;
    __syncthreads();
    if (team == 0) attn16[(size_t)(DOFF_ + b) * H_ + h * HD_ + d] = (__bf16)((acc + oacc[d]) * inv);
}

// ---------------------------------------------------------------- host launch
extern "C" void kernel_launch(void* const* d_in, const int* in_sizes, int n_in,
                              void* d_out, int out_size, void* d_ws, size_t ws_size,
                              hipStream_t stream)
{
    const float* hs     = (const float*)d_in[0];
    const float* wq     = (const float*)d_in[1];
    const float* wk     = (const float*)d_in[2];
    const float* wv     = (const float*)d_in[3];
    const float* wo     = (const float*)d_in[4];
    const float* la_q   = (const float*)d_in[5];
    const float* lb_q   = (const float*)d_in[6];
    const float* la_k   = (const float*)d_in[7];
    const float* lb_k   = (const float*)d_in[8];
    const float* la_v   = (const float*)d_in[9];
    const float* lb_v   = (const float*)d_in[10];
    const float* la_o   = (const float*)d_in[11];
    const float* lb_o   = (const float*)d_in[12];
    const float* kcache = (const float*)d_in[13];
    const float* vcache = (const float*)d_in[14];
    const int*   kvlen  = (const int*)d_in[15];
    float* out = (float*)d_out;

    float* qbuf    = (float*)d_ws;
    float* kbuf    = qbuf + (size_t)T_ * H_;
    float* vbuf    = kbuf + (size_t)T_ * H_;
    float* attnf   = vbuf + (size_t)T_ * H_;
    float* tmpbuf  = attnf + (size_t)T_ * H_;
    float* costab  = tmpbuf + (size_t)3 * T_ * RANK_;
    float* sintab  = costab + 1024 * 64;
    __bf16* hsb    = (__bf16*)(sintab + 1024 * 64);   // MPAD_ x H bf16 (hs, later attn)
    __bf16* wT     = hsb + (size_t)MPAD_ * H_;        // 3 x H x H bf16 = 12288 x 4096

    __bf16* q16 = (__bf16*)attnf;
    __bf16* k16 = q16 + (size_t)T_ * H_;
    __bf16* vT  = wT + (size_t)H_ * H_;               // reuse wk^T slot after QKV GEMM
    __bf16* attn16 = hsb;

    const int N8 = T_ * H_ / 8;

    rope_table_kernel<<<dim3(1024), dim3(64), 0, stream>>>(costab, sintab);
    convert_bf16_kernel<<<dim3(2048), dim3(256), 0, stream>>>(hs, hsb, N8);
    transpose_bf16_kernel<<<dim3(128, 128, 3), dim3(256), 0, stream>>>(
        wq, wk, wv, wT, wT + (size_t)H_ * H_, wT + (size_t)2 * H_ * H_);
    gemm_qkv<<<dim3(21, 48), dim3(512), 0, stream>>>(
        hsb, wT, qbuf, kbuf, vbuf, T_);
    lora_tmp_kernel<<<dim3(T_), dim3(256), 0, stream>>>(hs, la_q, la_k, la_v, tmpbuf);
    lora_rope_fused<<<dim3(T_), dim3(256), 0, stream>>>(qbuf, kbuf, vbuf, tmpbuf,
                                                        lb_q, lb_k, lb_v, kvlen,
                                                        costab, sintab, q16, k16);
    transpose_v_kernel<<<dim3(40, 32), dim3(256), 0, stream>>>(vbuf, vT);
    prefill_attn_mfma<<<dim3(40, 32), dim3(256), 0, stream>>>(q16, k16, vT, attn16);
    decode_attn_kernel<<<dim3(DEC_, NH_), dim3(256), 0, stream>>>(qbuf, kbuf, vbuf, kcache, vcache,
                                                                  kvlen, costab, sintab, attn16);
    transpose_bf16_kernel<<<dim3(128, 128, 1), dim3(256), 0, stream>>>(wo, wo, wo, wT, wT, wT);
    gemm_fused<<<dim3(11, 22), dim3(512), 0, stream>>>(
        attn16, wT, out, out, out, T_, H_);
    lora_tmp_bf16_kernel<<<dim3(T_), dim3(256), 0, stream>>>(attn16, la_o, tmpbuf);
    lora_add_kernel<<<dim3(T_, 16, 1), dim3(256), 0, stream>>>(tmpbuf, lb_o, lb_o, lb_o, out, out, out);
}

// Round 8
// 971.516 us; speedup vs baseline: 1.2369x; 1.1753x over previous
//
#include <hip/hip_runtime.h>
#include <hip/hip_bf16.h>

// LlamaAttentionWithLora on MI355X — round 8.
// LoRA folded into GEMM epilogues as a rank-64 bf16 MFMA (TMP16 @ WB16); GEMMs write bf16
// directly (no f32 q/k/v intermediate). rope16 is a slim bf16 pass over q,k only.
// lora_add deleted; decode reads bf16 q/k/v rows. GEMM K-loops unchanged from R7.

#define H_    4096
#define NH_   32
#define HD_   128
#define T_    2592
#define DOFF_ 2560
#define DEC_  32
#define LMAX_ 512
#define RANK_ 16
#define MPAD_ 2816

__constant__ float SCALE_ = 0.08838834764831845f; // 128^-0.5

typedef __bf16 bf16x8 __attribute__((ext_vector_type(8)));
typedef __bf16 bf16x4 __attribute__((ext_vector_type(4)));
typedef float  f32x4  __attribute__((ext_vector_type(4)));

__device__ __forceinline__ void async_cp16(const __bf16* g, __bf16* l) {
    __builtin_amdgcn_global_load_lds(
        (const __attribute__((address_space(1))) void*)g,
        (__attribute__((address_space(3))) void*)l, 16, 0, 0);
}

// ---------------------------------------------------------------- f32 -> bf16 convert
__global__ __launch_bounds__(256)
void convert_bf16_kernel(const float* __restrict__ src, __bf16* __restrict__ dst, int n8)
{
    const int stride = gridDim.x * blockDim.x;
    for (int i = blockIdx.x * blockDim.x + threadIdx.x; i < n8; i += stride) {
        float4 a = ((const float4*)src)[i * 2];
        float4 b = ((const float4*)src)[i * 2 + 1];
        bf16x8 w;
        w[0] = (__bf16)a.x; w[1] = (__bf16)a.y; w[2] = (__bf16)a.z; w[3] = (__bf16)a.w;
        w[4] = (__bf16)b.x; w[5] = (__bf16)b.y; w[6] = (__bf16)b.z; w[7] = (__bf16)b.w;
        ((bf16x8*)dst)[i] = w;
    }
}

// ---------------------------------------------------------------- f32 [K][N] -> bf16 [N][K]
__global__ __launch_bounds__(256)
void transpose_bf16_kernel(const float* __restrict__ W0, const float* __restrict__ W1,
                           const float* __restrict__ W2,
                           __bf16* __restrict__ T0, __bf16* __restrict__ T1, __bf16* __restrict__ T2)
{
    const float* W = (blockIdx.z == 0) ? W0 : (blockIdx.z == 1 ? W1 : W2);
    __bf16* To     = (blockIdx.z == 0) ? T0 : (blockIdx.z == 1 ? T1 : T2);
    __shared__ float s[32][33];
    const int bx = blockIdx.x * 32;
    const int by = blockIdx.y * 32;
    const int r  = threadIdx.x >> 3;
    const int c4 = (threadIdx.x & 7) * 4;
    float4 v = *(const float4*)&W[(size_t)(by + r) * H_ + bx + c4];
    s[r][c4] = v.x; s[r][c4 + 1] = v.y; s[r][c4 + 2] = v.z; s[r][c4 + 3] = v.w;
    __syncthreads();
    bf16x4 o;
    o[0] = (__bf16)s[c4 + 0][r]; o[1] = (__bf16)s[c4 + 1][r];
    o[2] = (__bf16)s[c4 + 2][r]; o[3] = (__bf16)s[c4 + 3][r];
    *(bf16x4*)&To[(size_t)(bx + r) * H_ + by + c4] = o;
}

// ---------------------------------------------------------------- LoRA stage 1: TMP16[z][r][64] (segment-expanded)
__global__ __launch_bounds__(256)
void lora_tmp_kernel(const float* __restrict__ X,
                     const float* __restrict__ la0, const float* __restrict__ la1,
                     const float* __restrict__ la2, __bf16* __restrict__ TMP16)
{
    const int r = blockIdx.x;
    const int si = (r < 648) ? 0 : (r < 1296 ? 1 : (r < 1944 ? 2 : 3));
    const int c    = threadIdx.x & 15;
    const int part = threadIdx.x >> 4;
    const float* xr = X + (size_t)r * H_;
    const float* wa0 = la0 + (size_t)si * H_ * RANK_;
    const float* wa1 = la1 + (size_t)si * H_ * RANK_;
    const float* wa2 = la2 + (size_t)si * H_ * RANK_;
    float s0 = 0.f, s1 = 0.f, s2 = 0.f;
    const int h0 = part * 256;
    for (int h = h0; h < h0 + 256; ++h) {
        const float xv = xr[h];
        s0 += xv * wa0[(size_t)h * RANK_ + c];
        s1 += xv * wa1[(size_t)h * RANK_ + c];
        s2 += xv * wa2[(size_t)h * RANK_ + c];
    }
    __shared__ float red[3][16][17];
    red[0][part][c] = s0; red[1][part][c] = s1; red[2][part][c] = s2;
    __syncthreads();
    if (threadIdx.x < 192) {
        const int z = threadIdx.x >> 6, cc = threadIdx.x & 63;
        float t = 0.f;
        if ((cc >> 4) == si) {
            #pragma unroll
            for (int p = 0; p < 16; ++p) t += red[z][p][cc & 15];
        }
        TMP16[((size_t)z * MPAD_ + r) * 64 + cc] = (__bf16)t;
    }
}

// ---------------------------------------------------------------- LoRA stage 1 (bf16 X) -> TMPo16[r][64]
__global__ __launch_bounds__(256)
void lora_tmp_bf16_kernel(const __bf16* __restrict__ X,
                          const float* __restrict__ la, __bf16* __restrict__ TMPo16)
{
    const int r = blockIdx.x;
    const int si = (r < 648) ? 0 : (r < 1296 ? 1 : (r < 1944 ? 2 : 3));
    const float* wa = la + (size_t)si * H_ * RANK_;
    const int c    = threadIdx.x & 15;
    const int part = threadIdx.x >> 4;
    const __bf16* xr = X + (size_t)r * H_;
    float s = 0.f;
    const int h0 = part * 256;
    for (int h = h0; h < h0 + 256; ++h) s += (float)xr[h] * wa[(size_t)h * RANK_ + c];
    __shared__ float red[16][17];
    red[part][c] = s;
    __syncthreads();
    if (threadIdx.x < 64) {
        const int cc = threadIdx.x;
        float t = 0.f;
        if ((cc >> 4) == si) {
            #pragma unroll
            for (int p = 0; p < 16; ++p) t += red[p][cc & 15];
        }
        TMPo16[(size_t)r * 64 + cc] = (__bf16)t;
    }
}

// ---------------------------------------------------------------- WB builders: WB16[col][64] per matrix
// z=0..2 -> WB16 cols z*4096..; z=3 -> WBo16.
__global__ __launch_bounds__(256)
void wb_build_kernel(const float* __restrict__ lbq, const float* __restrict__ lbk,
                     const float* __restrict__ lbv, const float* __restrict__ lbo,
                     __bf16* __restrict__ WB16, __bf16* __restrict__ WBo16)
{
    const int z = blockIdx.x;
    const int n = blockIdx.y * 256 + threadIdx.x;
    const float* lb = (z == 0) ? lbq : (z == 1 ? lbk : (z == 2 ? lbv : lbo));
    __bf16* dst = (z < 3) ? WB16 + ((size_t)z * H_ + n) * 64 : WBo16 + (size_t)n * 64;
    __bf16 row[64];
    #pragma unroll
    for (int si = 0; si < 4; ++si)
        #pragma unroll
        for (int c = 0; c < 16; ++c)
            row[si * 16 + c] = (__bf16)lb[((size_t)si * 16 + c) * H_ + n];
    #pragma unroll
    for (int i = 0; i < 8; ++i) *(bf16x8*)&dst[i * 8] = *(const bf16x8*)&row[i * 8];
}

// ---------------------------------------------------------------- QKV GEMM (128x256, BK=64, 3-buf ring)
// Writes bf16 q16/k16/v16 with fused lora delta. K-loop identical to round 7.
__global__ __launch_bounds__(512, 2)
void gemm_qkv(const __bf16* __restrict__ A, const __bf16* __restrict__ Bt,
              const __bf16* __restrict__ TMP16, const __bf16* __restrict__ WB16,
              __bf16* __restrict__ O0, __bf16* __restrict__ O1, __bf16* __restrict__ O2, int M)
{
    const int hw = blockIdx.y * 21 + blockIdx.x;
    const int work = (hw & 7) * 126 + (hw >> 3);     // 1008 = 8 * 126
    const int bm0 = (work % 21) * 128;
    const int bn0 = (work / 21) * 256;

    __shared__ __align__(16) __bf16 Asl[3][128 * 64];
    __shared__ __align__(16) __bf16 Bsl[3][256 * 64];

    const int tid = threadIdx.x, lane = tid & 63, wid = tid >> 6;
    const int wr = wid >> 2, wc = wid & 3;
    const int fr = lane & 15, fq = lane >> 4;

    int arow[2], aoff[2], brow[4], boff[4];
    #pragma unroll
    for (int i = 0; i < 2; ++i) {
        const int ci = i * 512 + tid;
        arow[i] = ci >> 3;
        aoff[i] = ((ci & 7) ^ (arow[i] & 7)) * 8;
    }
    #pragma unroll
    for (int i = 0; i < 4; ++i) {
        const int ci = i * 512 + tid;
        brow[i] = ci >> 3;
        boff[i] = ((ci & 7) ^ (brow[i] & 7)) * 8;
    }
    const __bf16* Ab = A  + (size_t)bm0 * H_;
    const __bf16* Bb = Bt + (size_t)bn0 * H_;

    auto stageA = [&](int buf, int kt2) {
        const int kb = kt2 * 64;
        #pragma unroll
        for (int i = 0; i < 2; ++i)
            async_cp16(Ab + (size_t)arow[i] * H_ + kb + aoff[i],
                       &Asl[buf][(i * 512 + wid * 64) * 8]);
    };
    auto stageB1 = [&](int buf, int kt2) {
        async_cp16(Bb + (size_t)brow[0] * H_ + kt2 * 64 + boff[0],
                   &Bsl[buf][(wid * 64) * 8]);
    };
    auto stageB3 = [&](int buf, int kt2) {
        const int kb = kt2 * 64;
        #pragma unroll
        for (int i = 1; i < 4; ++i)
            async_cp16(Bb + (size_t)brow[i] * H_ + kb + boff[i],
                       &Bsl[buf][(i * 512 + wid * 64) * 8]);
    };
    auto rdA = [&](int buf, int kh, int mi) -> bf16x8 {
        const int row = wr * 64 + mi * 16 + fr;
        const int pc  = (kh * 4 + fq) ^ (row & 7);
        return *(const bf16x8*)&Asl[buf][row * 64 + pc * 8];
    };
    auto rdB = [&](int buf, int kh, int nj) -> bf16x8 {
        const int row = wc * 64 + nj * 16 + fr;
        const int pc  = (kh * 4 + fq) ^ (row & 7);
        return *(const bf16x8*)&Bsl[buf][row * 64 + pc * 8];
    };

    f32x4 acc[4][4] = {};

    stageA(0, 0); stageB1(0, 0); stageB3(0, 0);
    stageA(1, 1); stageB1(1, 1); stageB3(1, 1);
    asm volatile("s_waitcnt vmcnt(6)");
    __builtin_amdgcn_sched_barrier(0);
    __builtin_amdgcn_s_barrier();

    const int NT = H_ / 64;
    int cur = 0, nxt = 2;
    for (int kt = 0; kt < NT; ++kt) {
        const bool pf = (kt + 2 < NT);
        bf16x8 af[4], bfr[4];

        #pragma unroll
        for (int mi = 0; mi < 4; ++mi) af[mi] = rdA(cur, 0, mi);
        #pragma unroll
        for (int nj = 0; nj < 4; ++nj) bfr[nj] = rdB(cur, 0, nj);
        if (pf) { stageA(nxt, kt + 2); stageB1(nxt, kt + 2); }
        __builtin_amdgcn_s_barrier();
        asm volatile("s_waitcnt lgkmcnt(0)");
        __builtin_amdgcn_sched_barrier(0);
        __builtin_amdgcn_s_setprio(1);
        #pragma unroll
        for (int mi = 0; mi < 4; ++mi)
            #pragma unroll
            for (int nj = 0; nj < 4; ++nj)
                acc[mi][nj] = __builtin_amdgcn_mfma_f32_16x16x32_bf16(af[mi], bfr[nj], acc[mi][nj], 0, 0, 0);
        __builtin_amdgcn_s_setprio(0);
        __builtin_amdgcn_s_barrier();

        #pragma unroll
        for (int mi = 0; mi < 4; ++mi) af[mi] = rdA(cur, 1, mi);
        #pragma unroll
        for (int nj = 0; nj < 4; ++nj) bfr[nj] = rdB(cur, 1, nj);
        if (pf) stageB3(nxt, kt + 2);
        __builtin_amdgcn_s_barrier();
        asm volatile("s_waitcnt lgkmcnt(0)");
        __builtin_amdgcn_sched_barrier(0);
        __builtin_amdgcn_s_setprio(1);
        #pragma unroll
        for (int mi = 0; mi < 4; ++mi)
            #pragma unroll
            for (int nj = 0; nj < 4; ++nj)
                acc[mi][nj] = __builtin_amdgcn_mfma_f32_16x16x32_bf16(af[mi], bfr[nj], acc[mi][nj], 0, 0, 0);
        __builtin_amdgcn_s_setprio(0);
        if (pf)               asm volatile("s_waitcnt vmcnt(6)");
        else if (kt + 1 < NT) asm volatile("s_waitcnt vmcnt(0)");
        __builtin_amdgcn_sched_barrier(0);
        __builtin_amdgcn_s_barrier();

        cur = (cur == 2) ? 0 : cur + 1;
        nxt = (nxt == 2) ? 0 : nxt + 1;
    }

    // epilogue: fused lora delta (rank-64 via 2 MFMA per fragment), bf16 store
    const int colbase = bn0 + wc * 64;
    const int mat = colbase >> 12;
    __bf16* O = (mat == 0) ? O0 : (mat == 1 ? O1 : O2);
    const __bf16* TPm = TMP16 + (size_t)mat * MPAD_ * 64;
    bf16x8 aT[4][2], bW[4][2];
    #pragma unroll
    for (int mi = 0; mi < 4; ++mi)
        #pragma unroll
        for (int kh = 0; kh < 2; ++kh)
            aT[mi][kh] = *(const bf16x8*)&TPm[(size_t)(bm0 + wr * 64 + mi * 16 + fr) * 64 + kh * 32 + fq * 8];
    #pragma unroll
    for (int nj = 0; nj < 4; ++nj)
        #pragma unroll
        for (int kh = 0; kh < 2; ++kh)
            bW[nj][kh] = *(const bf16x8*)&WB16[(size_t)(colbase + nj * 16 + fr) * 64 + kh * 32 + fq * 8];
    #pragma unroll
    for (int mi = 0; mi < 4; ++mi)
        #pragma unroll
        for (int nj = 0; nj < 4; ++nj) {
            acc[mi][nj] = __builtin_amdgcn_mfma_f32_16x16x32_bf16(aT[mi][0], bW[nj][0], acc[mi][nj], 0, 0, 0);
            acc[mi][nj] = __builtin_amdgcn_mfma_f32_16x16x32_bf16(aT[mi][1], bW[nj][1], acc[mi][nj], 0, 0, 0);
        }
    #pragma unroll
    for (int mi = 0; mi < 4; ++mi)
        #pragma unroll
        for (int nj = 0; nj < 4; ++nj) {
            const int cc = (colbase + nj * 16 + fr) & 4095;
            #pragma unroll
            for (int rr = 0; rr < 4; ++rr) {
                const int row = bm0 + wr * 64 + mi * 16 + fq * 4 + rr;
                if (row < M) O[(size_t)row * H_ + cc] = (__bf16)acc[mi][nj][rr];
            }
        }
}

// ---------------------------------------------------------------- O-proj GEMM (256x192, BK=64) + fused lora, f32 out
__global__ __launch_bounds__(512, 2)
void gemm_out(const __bf16* __restrict__ A, const __bf16* __restrict__ Bt,
              const __bf16* __restrict__ TMPo16, const __bf16* __restrict__ WBo16,
              float* __restrict__ C, int M, int Ntot)
{
    const int NY = gridDim.y;
    const int total = gridDim.x * NY;
    const int bid = blockIdx.x * NY + blockIdx.y;
    const int q = total >> 3, r8 = total & 7;
    const int xcd = bid & 7, j = bid >> 3;
    const int swz = (xcd < r8 ? xcd * (q + 1) : r8 * (q + 1) + (xcd - r8) * q) + j;
    const int bm0 = (swz / NY) * 256;
    const int bn0 = (swz % NY) * 192;

    __shared__ __align__(16) __bf16 Asl[2][256 * 64];
    __shared__ __align__(16) __bf16 Bsl[2][192 * 64];

    const int tid = threadIdx.x, lane = tid & 63, wid = tid >> 6;
    const int wr = wid >> 2, wc = wid & 3;
    const int fr = lane & 15, fq = lane >> 4;

    int arow[4], aoff[4], brow[3], boff[3];
    #pragma unroll
    for (int i = 0; i < 4; ++i) {
        const int ci = i * 512 + tid;
        arow[i] = ci >> 3;
        aoff[i] = ((ci & 7) ^ (arow[i] & 7)) * 8;
    }
    #pragma unroll
    for (int i = 0; i < 3; ++i) {
        const int ci = i * 512 + tid;
        brow[i] = ci >> 3;
        boff[i] = ((ci & 7) ^ (brow[i] & 7)) * 8;
    }
    const __bf16* Ab = A  + (size_t)bm0 * H_;
    const __bf16* Bb = Bt + (size_t)bn0 * H_;

    auto stage = [&](int buf, int kt1) {
        const int kb = kt1 * 64;
        #pragma unroll
        for (int i = 0; i < 4; ++i)
            async_cp16(Ab + (size_t)arow[i] * H_ + kb + aoff[i],
                       &Asl[buf][(i * 512 + wid * 64) * 8]);
        #pragma unroll
        for (int i = 0; i < 3; ++i)
            async_cp16(Bb + (size_t)brow[i] * H_ + kb + boff[i],
                       &Bsl[buf][(i * 512 + wid * 64) * 8]);
    };
    auto rdA = [&](int buf, int kh, int mi) -> bf16x8 {
        const int row = wr * 128 + mi * 16 + fr;
        const int kc  = kh * 4 + fq;
        return *(const bf16x8*)&Asl[buf][row * 64 + ((kc ^ (row & 7)) << 3)];
    };
    auto rdB = [&](int buf, int kh, int nj) -> bf16x8 {
        const int row = wc * 48 + nj * 16 + fr;
        const int kc  = kh * 4 + fq;
        return *(const bf16x8*)&Bsl[buf][row * 64 + ((kc ^ (row & 7)) << 3)];
    };

    f32x4 acc[8][3] = {};

    stage(0, 0);
    asm volatile("s_waitcnt vmcnt(0)");
    __builtin_amdgcn_sched_barrier(0);
    __builtin_amdgcn_s_barrier();

    const int NT = H_ / 64;
    for (int kt = 0; kt < NT; ++kt) {
        const int cur = kt & 1, nb = cur ^ 1;
        const bool pf = (kt + 1 < NT);
        bf16x8 af[8], bfr[3];

        #pragma unroll
        for (int mi = 0; mi < 8; ++mi) af[mi] = rdA(cur, 0, mi);
        #pragma unroll
        for (int nj = 0; nj < 3; ++nj) bfr[nj] = rdB(cur, 0, nj);
        if (pf) stage(nb, kt + 1);
        __builtin_amdgcn_s_barrier();
        asm volatile("s_waitcnt lgkmcnt(0)");
        __builtin_amdgcn_sched_barrier(0);
        __builtin_amdgcn_s_setprio(1);
        #pragma unroll
        for (int mi = 0; mi < 8; ++mi)
            #pragma unroll
            for (int nj = 0; nj < 3; ++nj)
                acc[mi][nj] = __builtin_amdgcn_mfma_f32_16x16x32_bf16(af[mi], bfr[nj], acc[mi][nj], 0, 0, 0);
        __builtin_amdgcn_s_setprio(0);
        __builtin_amdgcn_s_barrier();

        #pragma unroll
        for (int mi = 0; mi < 8; ++mi) af[mi] = rdA(cur, 1, mi);
        #pragma unroll
        for (int nj = 0; nj < 3; ++nj) bfr[nj] = rdB(cur, 1, nj);
        __builtin_amdgcn_s_barrier();
        asm volatile("s_waitcnt lgkmcnt(0)");
        __builtin_amdgcn_sched_barrier(0);
        __builtin_amdgcn_s_setprio(1);
        #pragma unroll
        for (int mi = 0; mi < 8; ++mi)
            #pragma unroll
            for (int nj = 0; nj < 3; ++nj)
                acc[mi][nj] = __builtin_amdgcn_mfma_f32_16x16x32_bf16(af[mi], bfr[nj], acc[mi][nj], 0, 0, 0);
        __builtin_amdgcn_s_setprio(0);
        asm volatile("s_waitcnt vmcnt(0)");
        __builtin_amdgcn_sched_barrier(0);
        __builtin_amdgcn_s_barrier();
    }

    // epilogue: fused lora delta + f32 store
    const int colw = bn0 + wc * 48;
    bf16x8 aT[8][2], bW[3][2];
    #pragma unroll
    for (int mi = 0; mi < 8; ++mi)
        #pragma unroll
        for (int kh = 0; kh < 2; ++kh)
            aT[mi][kh] = *(const bf16x8*)&TMPo16[(size_t)(bm0 + wr * 128 + mi * 16 + fr) * 64 + kh * 32 + fq * 8];
    #pragma unroll
    for (int nj = 0; nj < 3; ++nj)
        #pragma unroll
        for (int kh = 0; kh < 2; ++kh)
            bW[nj][kh] = *(const bf16x8*)&WBo16[(size_t)(colw + nj * 16 + fr) * 64 + kh * 32 + fq * 8];
    #pragma unroll
    for (int mi = 0; mi < 8; ++mi)
        #pragma unroll
        for (int nj = 0; nj < 3; ++nj) {
            acc[mi][nj] = __builtin_amdgcn_mfma_f32_16x16x32_bf16(aT[mi][0], bW[nj][0], acc[mi][nj], 0, 0, 0);
            acc[mi][nj] = __builtin_amdgcn_mfma_f32_16x16x32_bf16(aT[mi][1], bW[nj][1], acc[mi][nj], 0, 0, 0);
        }
    #pragma unroll
    for (int mi = 0; mi < 8; ++mi)
        #pragma unroll
        for (int nj = 0; nj < 3; ++nj) {
            const int col = colw + nj * 16 + fr;
            if (col < Ntot) {
                #pragma unroll
                for (int rr = 0; rr < 4; ++rr) {
                    const int row = bm0 + wr * 128 + mi * 16 + fq * 4 + rr;
                    if (row < M) C[(size_t)row * H_ + col] = acc[mi][nj][rr];
                }
            }
        }
}

// ---------------------------------------------------------------- RoPE tables
__global__ void rope_table_kernel(float* __restrict__ cost, float* __restrict__ sint)
{
    const int p = blockIdx.x;
    const int i = threadIdx.x;
    const float inv = powf(10000.f, -(float)(2 * i) / (float)HD_);
    const float a = (float)p * inv;
    cost[p * 64 + i] = cosf(a);
    sint[p * 64 + i] = sinf(a);
}

// ---------------------------------------------------------------- rope16: in-place rope on bf16 q (all rows), k (prefill rows)
__global__ __launch_bounds__(256)
void rope16_kernel(__bf16* __restrict__ q16, __bf16* __restrict__ k16,
                   const int* __restrict__ kv_lens,
                   const float* __restrict__ cost, const float* __restrict__ sint)
{
    const int r = blockIdx.x;
    int pos; bool dok;
    if (r < DOFF_) {
        if      (r < 1024) pos = r;
        else if (r < 1536) pos = r - 1024;
        else if (r < 2304) pos = r - 1536;
        else               pos = r - 2304;
        dok = true;
    } else {
        pos = kv_lens[r - DOFF_];
        dok = false;
    }
    const int tid = threadIdx.x;
    const int h = tid >> 3, sub = tid & 7;
    const int i0 = sub * 8;
    const size_t b1 = (size_t)r * H_ + h * HD_ + i0;
    const size_t b2 = b1 + 64;

    float cs[8], sn[8];
    #pragma unroll
    for (int j = 0; j < 8; ++j) { cs[j] = cost[pos * 64 + i0 + j]; sn[j] = sint[pos * 64 + i0 + j]; }

    {
        bf16x8 x1 = *(const bf16x8*)&q16[b1], x2 = *(const bf16x8*)&q16[b2];
        bf16x8 o1, o2;
        #pragma unroll
        for (int j = 0; j < 8; ++j) {
            const float f1 = (float)x1[j], f2 = (float)x2[j];
            o1[j] = (__bf16)(f1 * cs[j] - f2 * sn[j]);
            o2[j] = (__bf16)(f2 * cs[j] + f1 * sn[j]);
        }
        *(bf16x8*)&q16[b1] = o1; *(bf16x8*)&q16[b2] = o2;
    }
    if (dok) {
        bf16x8 x1 = *(const bf16x8*)&k16[b1], x2 = *(const bf16x8*)&k16[b2];
        bf16x8 o1, o2;
        #pragma unroll
        for (int j = 0; j < 8; ++j) {
            const float f1 = (float)x1[j], f2 = (float)x2[j];
            o1[j] = (__bf16)(f1 * cs[j] - f2 * sn[j]);
            o2[j] = (__bf16)(f2 * cs[j] + f1 * sn[j]);
        }
        *(bf16x8*)&k16[b1] = o1; *(bf16x8*)&k16[b2] = o2;
    }
}

// ---------------------------------------------------------------- V transpose per head (bf16 in)
__global__ __launch_bounds__(256)
void transpose_v_kernel(const __bf16* __restrict__ v16, __bf16* __restrict__ vT)
{
    __shared__ __bf16 s[64][136];
    const int tb = blockIdx.x;
    const int h  = blockIdx.y;
    const int tid = threadIdx.x;
    #pragma unroll
    for (int i = 0; i < 4; ++i) {
        const int idx = i * 256 + tid;              // 0..1023 chunks of 8
        const int row = idx >> 4;
        const int c8  = (idx & 15) * 8;
        *(bf16x8*)&s[row][c8] = *(const bf16x8*)&v16[(size_t)(tb * 64 + row) * H_ + h * HD_ + c8];
    }
    __syncthreads();
    #pragma unroll
    for (int i = 0; i < 4; ++i) {
        const int idx = i * 256 + tid;
        const int d = idx >> 3;
        const int c = idx & 7;
        bf16x8 w;
        #pragma unroll
        for (int j = 0; j < 8; ++j) w[j] = s[c * 8 + j][d];
        *(bf16x8*)&vT[(size_t)(h * HD_ + d) * T_ + tb * 64 + c * 8] = w;
    }
}

// ---------------------------------------------------------------- prefill attention (MFMA bf16, flash)
__global__ __launch_bounds__(256)
void prefill_attn_mfma(const __bf16* __restrict__ q16, const __bf16* __restrict__ k16,
                       const __bf16* __restrict__ vT, __bf16* __restrict__ attn16)
{
    const int qb = blockIdx.x;
    int soff, qoff;
    if      (qb < 16) { soff = 0;    qoff = qb * 64; }
    else if (qb < 24) { soff = 1024; qoff = (qb - 16) * 64; }
    else if (qb < 36) { soff = 1536; qoff = (qb - 24) * 64; }
    else              { soff = 2304; qoff = (qb - 36) * 64; }
    const int h = blockIdx.y;

    __shared__ __align__(16) __bf16 Kl[64 * 128];
    __shared__ __align__(16) __bf16 Vl[128 * 64];
    __shared__ __align__(16) __bf16 Pl[4][16 * 64];

    const int tid = threadIdx.x, lane = tid & 63, wid = tid >> 6;
    const int fr = lane & 15, fq = lane >> 4;

    const int grow0 = soff + qoff + wid * 16;
    bf16x8 qf[4];
    #pragma unroll
    for (int ks = 0; ks < 4; ++ks)
        qf[ks] = *(const bf16x8*)&q16[(size_t)(grow0 + fr) * H_ + h * HD_ + ks * 32 + fq * 8];

    float m[4], l[4];
    #pragma unroll
    for (int r = 0; r < 4; ++r) { m[r] = -1e30f; l[r] = 0.f; }
    f32x4 o[8] = {};

    const int ntiles = qoff / 64 + 1;
    for (int t = 0; t < ntiles; ++t) {
        const int kt = t * 64;
        #pragma unroll
        for (int i = 0; i < 4; ++i) {
            const int chunk = i * 256 + tid;
            const int row = chunk >> 4, c = chunk & 15;
            async_cp16(k16 + (size_t)(soff + kt + row) * H_ + h * HD_ + ((c ^ (row & 7)) * 8),
                       Kl + (size_t)(i * 256 + wid * 64) * 8);
        }
        #pragma unroll
        for (int i = 0; i < 4; ++i) {
            const int chunk = i * 256 + tid;
            const int row = chunk >> 3, c = chunk & 7;
            async_cp16(vT + (size_t)(h * HD_ + row) * T_ + soff + kt + ((c ^ (row & 7)) * 8),
                       Vl + (size_t)(i * 256 + wid * 64) * 8);
        }
        __syncthreads();

        f32x4 s[4] = {};
        #pragma unroll
        for (int sub = 0; sub < 4; ++sub)
            #pragma unroll
            for (int ks = 0; ks < 4; ++ks) {
                bf16x8 b = *(const bf16x8*)&Kl[(sub * 16 + fr) * 128 + (((ks * 4 + fq) ^ (fr & 7)) * 8)];
                s[sub] = __builtin_amdgcn_mfma_f32_16x16x32_bf16(qf[ks], b, s[sub], 0, 0, 0);
            }

        float p[4][4];
        #pragma unroll
        for (int sub = 0; sub < 4; ++sub)
            #pragma unroll
            for (int r = 0; r < 4; ++r) {
                const int qpos = qoff + wid * 16 + fq * 4 + r;
                const int kpos = kt + sub * 16 + fr;
                p[sub][r] = (kpos <= qpos) ? s[sub][r] * SCALE_ : -1e30f;
            }
        float fsc[4];
        #pragma unroll
        for (int r = 0; r < 4; ++r) {
            float tm = fmaxf(fmaxf(p[0][r], p[1][r]), fmaxf(p[2][r], p[3][r]));
            tm = fmaxf(tm, __shfl_xor(tm, 1));
            tm = fmaxf(tm, __shfl_xor(tm, 2));
            tm = fmaxf(tm, __shfl_xor(tm, 4));
            tm = fmaxf(tm, __shfl_xor(tm, 8));
            const float mn = fmaxf(m[r], tm);
            fsc[r] = __expf(m[r] - mn);
            m[r] = mn;
            float ls = 0.f;
            #pragma unroll
            for (int sub = 0; sub < 4; ++sub) {
                p[sub][r] = __expf(p[sub][r] - mn);
                ls += p[sub][r];
            }
            l[r] = l[r] * fsc[r] + ls;
        }
        #pragma unroll
        for (int c = 0; c < 8; ++c)
            #pragma unroll
            for (int r = 0; r < 4; ++r) o[c][r] *= fsc[r];

        #pragma unroll
        for (int sub = 0; sub < 4; ++sub)
            #pragma unroll
            for (int r = 0; r < 4; ++r) {
                const int qr = fq * 4 + r;
                Pl[wid][qr * 64 + ((sub * 16 + fr) ^ ((qr & 7) << 3))] = (__bf16)p[sub][r];
            }
        bf16x8 pa[2];
        #pragma unroll
        for (int a = 0; a < 2; ++a)
            pa[a] = *(const bf16x8*)&Pl[wid][fr * 64 + (((a * 4 + fq) ^ (fr & 7)) * 8)];

        #pragma unroll
        for (int a = 0; a < 2; ++a)
            #pragma unroll
            for (int c = 0; c < 8; ++c) {
                bf16x8 bv = *(const bf16x8*)&Vl[(c * 16 + fr) * 64 + (((a * 4 + fq) ^ (fr & 7)) * 8)];
                o[c] = __builtin_amdgcn_mfma_f32_16x16x32_bf16(pa[a], bv, o[c], 0, 0, 0);
            }
        __syncthreads();
    }

    float inv[4];
    #pragma unroll
    for (int r = 0; r < 4; ++r) {
        float ls = l[r];
        ls += __shfl_xor(ls, 1); ls += __shfl_xor(ls, 2);
        ls += __shfl_xor(ls, 4); ls += __shfl_xor(ls, 8);
        inv[r] = 1.f / ls;
    }
    #pragma unroll
    for (int c = 0; c < 8; ++c)
        #pragma unroll
        for (int r = 0; r < 4; ++r)
            attn16[(size_t)(grow0 + fq * 4 + r) * H_ + h * HD_ + c * 16 + fr] = (__bf16)(o[c][r] * inv[r]);
}

// ---------------------------------------------------------------- decode attention (bf16 q/k/v rows, f32 caches)
__global__ __launch_bounds__(256)
void decode_attn_kernel(const __bf16* __restrict__ q16, const __bf16* __restrict__ k16,
                        const __bf16* __restrict__ v16, const float* __restrict__ kc,
                        const float* __restrict__ vc, const int* __restrict__ kv_lens,
                        const float* __restrict__ cost, const float* __restrict__ sint,
                        __bf16* __restrict__ attn16)
{
    const int b = blockIdx.x, h = blockIdx.y;
    const int kvlen = kv_lens[b];
    const int L = kvlen + 1;
    const int tid = threadIdx.x, lane = tid & 63, w = tid >> 6;

    __shared__ float sc_s[LMAX_];
    __shared__ float red[4];
    __shared__ float oacc[HD_];

    const __bf16* qrow = q16 + (size_t)(DOFF_ + b) * H_ + h * HD_;
    const float q1 = (float)qrow[lane], q2 = (float)qrow[lane + 64];
    const __bf16* kdrow = k16 + (size_t)(DOFF_ + b) * H_ + h * HD_;

    for (int l = w; l < L; l += 4) {
        float k1, k2;
        if (l == kvlen) { k1 = (float)kdrow[lane]; k2 = (float)kdrow[lane + 64]; }
        else {
            const float* src = kc + (((size_t)b * LMAX_ + l) * NH_ + h) * HD_;
            k1 = src[lane]; k2 = src[lane + 64];
        }
        const float c = cost[l * 64 + lane], s = sint[l * 64 + lane];
        float d = q1 * (k1 * c - k2 * s) + q2 * (k2 * c + k1 * s);
        #pragma unroll
        for (int off = 1; off < 64; off <<= 1) d += __shfl_xor(d, off);
        if (lane == 0) sc_s[l] = d * SCALE_;
    }
    __syncthreads();

    float mx = -1e30f;
    for (int i = tid; i < L; i += 256) mx = fmaxf(mx, sc_s[i]);
    #pragma unroll
    for (int off = 1; off < 64; off <<= 1) mx = fmaxf(mx, __shfl_xor(mx, off));
    if (lane == 0) red[w] = mx;
    __syncthreads();
    mx = fmaxf(fmaxf(red[0], red[1]), fmaxf(red[2], red[3]));
    __syncthreads();

    float sum = 0.f;
    for (int i = tid; i < L; i += 256) { const float e = __expf(sc_s[i] - mx); sc_s[i] = e; sum += e; }
    #pragma unroll
    for (int off = 1; off < 64; off <<= 1) sum += __shfl_xor(sum, off);
    if (lane == 0) red[w] = sum;
    __syncthreads();
    sum = red[0] + red[1] + red[2] + red[3];
    const float inv = 1.f / sum;

    const int d = tid & 127, team = tid >> 7;
    const __bf16* vdrow = v16 + (size_t)(DOFF_ + b) * H_ + h * HD_;
    float acc = 0.f;
    for (int l = team; l < L; l += 2) {
        float vv;
        if (l == kvlen) vv = (float)vdrow[d];
        else            vv = vc[(((size_t)b * LMAX_ + l) * NH_ + h) * HD_ + d];
        acc += sc_s[l] * vv;
    }
    if (team == 1) oacc[d] = acc;
    __syncthreads();
    if (team == 0) attn16[(size_t)(DOFF_ + b) * H_ + h * HD_ + d] = (__bf16)((acc + oacc[d]) * inv);
}

// ---------------------------------------------------------------- host launch
extern "C" void kernel_launch(void* const* d_in, const int* in_sizes, int n_in,
                              void* d_out, int out_size, void* d_ws, size_t ws_size,
                              hipStream_t stream)
{
    const float* hs     = (const float*)d_in[0];
    const float* wq     = (const float*)d_in[1];
    const float* wk     = (const float*)d_in[2];
    const float* wv     = (const float*)d_in[3];
    const float* wo     = (const float*)d_in[4];
    const float* la_q   = (const float*)d_in[5];
    const float* lb_q   = (const float*)d_in[6];
    const float* la_k   = (const float*)d_in[7];
    const float* lb_k   = (const float*)d_in[8];
    const float* la_v   = (const float*)d_in[9];
    const float* lb_v   = (const float*)d_in[10];
    const float* la_o   = (const float*)d_in[11];
    const float* lb_o   = (const float*)d_in[12];
    const float* kcache = (const float*)d_in[13];
    const float* vcache = (const float*)d_in[14];
    const int*   kvlen  = (const int*)d_in[15];
    float* out = (float*)d_out;

    float*  costab = (float*)d_ws;
    float*  sintab = costab + 1024 * 64;
    __bf16* TMP16  = (__bf16*)(sintab + 1024 * 64);       // [3][MPAD][64]
    __bf16* TMPo16 = TMP16 + (size_t)3 * MPAD_ * 64;      // [MPAD][64]
    __bf16* WB16   = TMPo16 + (size_t)MPAD_ * 64;         // [12288][64]
    __bf16* WBo16  = WB16 + (size_t)3 * H_ * 64;          // [4352][64] (padded)
    __bf16* q16    = WBo16 + (size_t)4352 * 64;           // [T][H]
    __bf16* k16    = q16 + (size_t)T_ * H_;
    __bf16* v16    = k16 + (size_t)T_ * H_;
    __bf16* hsb    = v16 + (size_t)T_ * H_;               // [MPAD][H]: hs bf16, later attn16
    __bf16* wT     = hsb + (size_t)MPAD_ * H_;            // [3][H][H]
    __bf16* vT     = wT + (size_t)H_ * H_;                // reuse wk^T slot after QKV GEMM
    __bf16* attn16 = hsb;

    const int N8 = T_ * H_ / 8;

    rope_table_kernel<<<dim3(1024), dim3(64), 0, stream>>>(costab, sintab);
    convert_bf16_kernel<<<dim3(2048), dim3(256), 0, stream>>>(hs, hsb, N8);
    transpose_bf16_kernel<<<dim3(128, 128, 3), dim3(256), 0, stream>>>(
        wq, wk, wv, wT, wT + (size_t)H_ * H_, wT + (size_t)2 * H_ * H_);
    lora_tmp_kernel<<<dim3(T_), dim3(256), 0, stream>>>(hs, la_q, la_k, la_v, TMP16);
    wb_build_kernel<<<dim3(4, 16), dim3(256), 0, stream>>>(lb_q, lb_k, lb_v, lb_o, WB16, WBo16);
    gemm_qkv<<<dim3(21, 48), dim3(512), 0, stream>>>(
        hsb, wT, TMP16, WB16, q16, k16, v16, T_);
    rope16_kernel<<<dim3(T_), dim3(256), 0, stream>>>(q16, k16, kvlen, costab, sintab);
    transpose_v_kernel<<<dim3(40, 32), dim3(256), 0, stream>>>(v16, vT);
    prefill_attn_mfma<<<dim3(40, 32), dim3(256), 0, stream>>>(q16, k16, vT, attn16);
    decode_attn_kernel<<<dim3(DEC_, NH_), dim3(256), 0, stream>>>(q16, k16, v16, kcache, vcache,
                                                                  kvlen, costab, sintab, attn16);
    transpose_bf16_kernel<<<dim3(128, 128, 1), dim3(256), 0, stream>>>(wo, wo, wo, wT, wT, wT);
    lora_tmp_bf16_kernel<<<dim3(T_), dim3(256), 0, stream>>>(attn16, la_o, TMPo16);
    gemm_out<<<dim3(11, 22), dim3(512), 0, stream>>>(
        attn16, wT, TMPo16, WBo16, out, T_, H_);
}

// Round 9
// 941.993 us; speedup vs baseline: 1.2757x; 1.0313x over previous
//
#include <hip/hip_runtime.h>
#include <hip/hip_bf16.h>

// LlamaAttentionWithLora on MI355X — round 9.
// Changes vs R8: (1) transpose v2 (64x64 tiles, bf16x8 writes); (2) prefill attention
// double-buffered K/V + counted vmcnt + setprio + defer-max rescale; (3) convert+lora_tmp
// fused into hs_prep. GEMMs unchanged (R7 QKV ring / R6 O-proj + fused LoRA epilogues).

#define H_    4096
#define NH_   32
#define HD_   128
#define T_    2592
#define DOFF_ 2560
#define DEC_  32
#define LMAX_ 512
#define RANK_ 16
#define MPAD_ 2816

__constant__ float SCALE_ = 0.08838834764831845f; // 128^-0.5

typedef __bf16 bf16x8 __attribute__((ext_vector_type(8)));
typedef __bf16 bf16x4 __attribute__((ext_vector_type(4)));
typedef float  f32x4  __attribute__((ext_vector_type(4)));

__device__ __forceinline__ void async_cp16(const __bf16* g, __bf16* l) {
    __builtin_amdgcn_global_load_lds(
        (const __attribute__((address_space(1))) void*)g,
        (__attribute__((address_space(3))) void*)l, 16, 0, 0);
}

// ---------------------------------------------------------------- hs prep: bf16 convert + lora_tmp fused
__global__ __launch_bounds__(256)
void hs_prep_kernel(const float* __restrict__ X, __bf16* __restrict__ Xb,
                    const float* __restrict__ la0, const float* __restrict__ la1,
                    const float* __restrict__ la2, __bf16* __restrict__ TMP16)
{
    const int r = blockIdx.x;
    const int tid = threadIdx.x;
    const float* xr = X + (size_t)r * H_;
    __bf16* br = Xb + (size_t)r * H_;
    #pragma unroll
    for (int i = 0; i < 4; ++i) {
        float4 v = ((const float4*)xr)[tid + i * 256];
        bf16x4 w; w[0] = (__bf16)v.x; w[1] = (__bf16)v.y; w[2] = (__bf16)v.z; w[3] = (__bf16)v.w;
        ((bf16x4*)br)[tid + i * 256] = w;
    }

    const int si = (r < 648) ? 0 : (r < 1296 ? 1 : (r < 1944 ? 2 : 3));
    const int c    = tid & 15;
    const int part = tid >> 4;
    const float* wa0 = la0 + (size_t)si * H_ * RANK_;
    const float* wa1 = la1 + (size_t)si * H_ * RANK_;
    const float* wa2 = la2 + (size_t)si * H_ * RANK_;
    float s0 = 0.f, s1 = 0.f, s2 = 0.f;
    const int h0 = part * 256;
    for (int h = h0; h < h0 + 256; ++h) {
        const float xv = xr[h];
        s0 += xv * wa0[(size_t)h * RANK_ + c];
        s1 += xv * wa1[(size_t)h * RANK_ + c];
        s2 += xv * wa2[(size_t)h * RANK_ + c];
    }
    __shared__ float red[3][16][17];
    red[0][part][c] = s0; red[1][part][c] = s1; red[2][part][c] = s2;
    __syncthreads();
    if (tid < 192) {
        const int z = tid >> 6, cc = tid & 63;
        float t = 0.f;
        if ((cc >> 4) == si) {
            #pragma unroll
            for (int p = 0; p < 16; ++p) t += red[z][p][cc & 15];
        }
        TMP16[((size_t)z * MPAD_ + r) * 64 + cc] = (__bf16)t;
    }
}

// ---------------------------------------------------------------- f32 [K][N] -> bf16 [N][K], 64x64 tiles
__global__ __launch_bounds__(256)
void transpose_bf16_kernel(const float* __restrict__ W0, const float* __restrict__ W1,
                           const float* __restrict__ W2,
                           __bf16* __restrict__ T0, __bf16* __restrict__ T1, __bf16* __restrict__ T2)
{
    const float* W = (blockIdx.z == 0) ? W0 : (blockIdx.z == 1 ? W1 : W2);
    __bf16* To     = (blockIdx.z == 0) ? T0 : (blockIdx.z == 1 ? T1 : T2);
    __shared__ float s[64][65];
    const int bx = blockIdx.x * 64;   // col of W = out row (n)
    const int by = blockIdx.y * 64;   // row of W = out col (k)
    const int tid = threadIdx.x;
    #pragma unroll
    for (int i = 0; i < 4; ++i) {
        const int idx = i * 256 + tid;          // 0..1023 float4 slots
        const int r  = idx >> 4;                // 0..63 (k-local)
        const int c4 = (idx & 15) * 4;          // 0..60 (n-local)
        float4 v = *(const float4*)&W[(size_t)(by + r) * H_ + bx + c4];
        s[r][c4] = v.x; s[r][c4 + 1] = v.y; s[r][c4 + 2] = v.z; s[r][c4 + 3] = v.w;
    }
    __syncthreads();
    #pragma unroll
    for (int i = 0; i < 2; ++i) {
        const int idx = i * 256 + tid;          // 0..511 chunks
        const int n  = idx >> 3;                // 0..63
        const int kc = (idx & 7) * 8;           // 0..56
        bf16x8 w;
        #pragma unroll
        for (int j = 0; j < 8; ++j) w[j] = (__bf16)s[kc + j][n];
        *(bf16x8*)&To[(size_t)(bx + n) * H_ + by + kc] = w;
    }
}

// ---------------------------------------------------------------- LoRA stage 1 (bf16 X) -> TMPo16[r][64]
__global__ __launch_bounds__(256)
void lora_tmp_bf16_kernel(const __bf16* __restrict__ X,
                          const float* __restrict__ la, __bf16* __restrict__ TMPo16)
{
    const int r = blockIdx.x;
    const int si = (r < 648) ? 0 : (r < 1296 ? 1 : (r < 1944 ? 2 : 3));
    const float* wa = la + (size_t)si * H_ * RANK_;
    const int c    = threadIdx.x & 15;
    const int part = threadIdx.x >> 4;
    const __bf16* xr = X + (size_t)r * H_;
    float s = 0.f;
    const int h0 = part * 256;
    for (int h = h0; h < h0 + 256; ++h) s += (float)xr[h] * wa[(size_t)h * RANK_ + c];
    __shared__ float red[16][17];
    red[part][c] = s;
    __syncthreads();
    if (threadIdx.x < 64) {
        const int cc = threadIdx.x;
        float t = 0.f;
        if ((cc >> 4) == si) {
            #pragma unroll
            for (int p = 0; p < 16; ++p) t += red[p][cc & 15];
        }
        TMPo16[(size_t)r * 64 + cc] = (__bf16)t;
    }
}

// ---------------------------------------------------------------- WB builders
__global__ __launch_bounds__(256)
void wb_build_kernel(const float* __restrict__ lbq, const float* __restrict__ lbk,
                     const float* __restrict__ lbv, const float* __restrict__ lbo,
                     __bf16* __restrict__ WB16, __bf16* __restrict__ WBo16)
{
    const int z = blockIdx.x;
    const int n = blockIdx.y * 256 + threadIdx.x;
    const float* lb = (z == 0) ? lbq : (z == 1 ? lbk : (z == 2 ? lbv : lbo));
    __bf16* dst = (z < 3) ? WB16 + ((size_t)z * H_ + n) * 64 : WBo16 + (size_t)n * 64;
    __bf16 row[64];
    #pragma unroll
    for (int si = 0; si < 4; ++si)
        #pragma unroll
        for (int c = 0; c < 16; ++c)
            row[si * 16 + c] = (__bf16)lb[((size_t)si * 16 + c) * H_ + n];
    #pragma unroll
    for (int i = 0; i < 8; ++i) *(bf16x8*)&dst[i * 8] = *(const bf16x8*)&row[i * 8];
}

// ---------------------------------------------------------------- QKV GEMM (128x256, BK=64, 3-buf ring) + fused lora, bf16 out
__global__ __launch_bounds__(512, 2)
void gemm_qkv(const __bf16* __restrict__ A, const __bf16* __restrict__ Bt,
              const __bf16* __restrict__ TMP16, const __bf16* __restrict__ WB16,
              __bf16* __restrict__ O0, __bf16* __restrict__ O1, __bf16* __restrict__ O2, int M)
{
    const int hw = blockIdx.y * 21 + blockIdx.x;
    const int work = (hw & 7) * 126 + (hw >> 3);     // 1008 = 8 * 126
    const int bm0 = (work % 21) * 128;
    const int bn0 = (work / 21) * 256;

    __shared__ __align__(16) __bf16 Asl[3][128 * 64];
    __shared__ __align__(16) __bf16 Bsl[3][256 * 64];

    const int tid = threadIdx.x, lane = tid & 63, wid = tid >> 6;
    const int wr = wid >> 2, wc = wid & 3;
    const int fr = lane & 15, fq = lane >> 4;

    int arow[2], aoff[2], brow[4], boff[4];
    #pragma unroll
    for (int i = 0; i < 2; ++i) {
        const int ci = i * 512 + tid;
        arow[i] = ci >> 3;
        aoff[i] = ((ci & 7) ^ (arow[i] & 7)) * 8;
    }
    #pragma unroll
    for (int i = 0; i < 4; ++i) {
        const int ci = i * 512 + tid;
        brow[i] = ci >> 3;
        boff[i] = ((ci & 7) ^ (brow[i] & 7)) * 8;
    }
    const __bf16* Ab = A  + (size_t)bm0 * H_;
    const __bf16* Bb = Bt + (size_t)bn0 * H_;

    auto stageA = [&](int buf, int kt2) {
        const int kb = kt2 * 64;
        #pragma unroll
        for (int i = 0; i < 2; ++i)
            async_cp16(Ab + (size_t)arow[i] * H_ + kb + aoff[i],
                       &Asl[buf][(i * 512 + wid * 64) * 8]);
    };
    auto stageB1 = [&](int buf, int kt2) {
        async_cp16(Bb + (size_t)brow[0] * H_ + kt2 * 64 + boff[0],
                   &Bsl[buf][(wid * 64) * 8]);
    };
    auto stageB3 = [&](int buf, int kt2) {
        const int kb = kt2 * 64;
        #pragma unroll
        for (int i = 1; i < 4; ++i)
            async_cp16(Bb + (size_t)brow[i] * H_ + kb + boff[i],
                       &Bsl[buf][(i * 512 + wid * 64) * 8]);
    };
    auto rdA = [&](int buf, int kh, int mi) -> bf16x8 {
        const int row = wr * 64 + mi * 16 + fr;
        const int pc  = (kh * 4 + fq) ^ (row & 7);
        return *(const bf16x8*)&Asl[buf][row * 64 + pc * 8];
    };
    auto rdB = [&](int buf, int kh, int nj) -> bf16x8 {
        const int row = wc * 64 + nj * 16 + fr;
        const int pc  = (kh * 4 + fq) ^ (row & 7);
        return *(const bf16x8*)&Bsl[buf][row * 64 + pc * 8];
    };

    f32x4 acc[4][4] = {};

    stageA(0, 0); stageB1(0, 0); stageB3(0, 0);
    stageA(1, 1); stageB1(1, 1); stageB3(1, 1);
    asm volatile("s_waitcnt vmcnt(6)");
    __builtin_amdgcn_sched_barrier(0);
    __builtin_amdgcn_s_barrier();

    const int NT = H_ / 64;
    int cur = 0, nxt = 2;
    for (int kt = 0; kt < NT; ++kt) {
        const bool pf = (kt + 2 < NT);
        bf16x8 af[4], bfr[4];

        #pragma unroll
        for (int mi = 0; mi < 4; ++mi) af[mi] = rdA(cur, 0, mi);
        #pragma unroll
        for (int nj = 0; nj < 4; ++nj) bfr[nj] = rdB(cur, 0, nj);
        if (pf) { stageA(nxt, kt + 2); stageB1(nxt, kt + 2); }
        __builtin_amdgcn_s_barrier();
        asm volatile("s_waitcnt lgkmcnt(0)");
        __builtin_amdgcn_sched_barrier(0);
        __builtin_amdgcn_s_setprio(1);
        #pragma unroll
        for (int mi = 0; mi < 4; ++mi)
            #pragma unroll
            for (int nj = 0; nj < 4; ++nj)
                acc[mi][nj] = __builtin_amdgcn_mfma_f32_16x16x32_bf16(af[mi], bfr[nj], acc[mi][nj], 0, 0, 0);
        __builtin_amdgcn_s_setprio(0);
        __builtin_amdgcn_s_barrier();

        #pragma unroll
        for (int mi = 0; mi < 4; ++mi) af[mi] = rdA(cur, 1, mi);
        #pragma unroll
        for (int nj = 0; nj < 4; ++nj) bfr[nj] = rdB(cur, 1, nj);
        if (pf) stageB3(nxt, kt + 2);
        __builtin_amdgcn_s_barrier();
        asm volatile("s_waitcnt lgkmcnt(0)");
        __builtin_amdgcn_sched_barrier(0);
        __builtin_amdgcn_s_setprio(1);
        #pragma unroll
        for (int mi = 0; mi < 4; ++mi)
            #pragma unroll
            for (int nj = 0; nj < 4; ++nj)
                acc[mi][nj] = __builtin_amdgcn_mfma_f32_16x16x32_bf16(af[mi], bfr[nj], acc[mi][nj], 0, 0, 0);
        __builtin_amdgcn_s_setprio(0);
        if (pf)               asm volatile("s_waitcnt vmcnt(6)");
        else if (kt + 1 < NT) asm volatile("s_waitcnt vmcnt(0)");
        __builtin_amdgcn_sched_barrier(0);
        __builtin_amdgcn_s_barrier();

        cur = (cur == 2) ? 0 : cur + 1;
        nxt = (nxt == 2) ? 0 : nxt + 1;
    }

    const int colbase = bn0 + wc * 64;
    const int mat = colbase >> 12;
    __bf16* O = (mat == 0) ? O0 : (mat == 1 ? O1 : O2);
    const __bf16* TPm = TMP16 + (size_t)mat * MPAD_ * 64;
    bf16x8 aT[4][2], bW[4][2];
    #pragma unroll
    for (int mi = 0; mi < 4; ++mi)
        #pragma unroll
        for (int kh = 0; kh < 2; ++kh)
            aT[mi][kh] = *(const bf16x8*)&TPm[(size_t)(bm0 + wr * 64 + mi * 16 + fr) * 64 + kh * 32 + fq * 8];
    #pragma unroll
    for (int nj = 0; nj < 4; ++nj)
        #pragma unroll
        for (int kh = 0; kh < 2; ++kh)
            bW[nj][kh] = *(const bf16x8*)&WB16[(size_t)(colbase + nj * 16 + fr) * 64 + kh * 32 + fq * 8];
    #pragma unroll
    for (int mi = 0; mi < 4; ++mi)
        #pragma unroll
        for (int nj = 0; nj < 4; ++nj) {
            acc[mi][nj] = __builtin_amdgcn_mfma_f32_16x16x32_bf16(aT[mi][0], bW[nj][0], acc[mi][nj], 0, 0, 0);
            acc[mi][nj] = __builtin_amdgcn_mfma_f32_16x16x32_bf16(aT[mi][1], bW[nj][1], acc[mi][nj], 0, 0, 0);
        }
    #pragma unroll
    for (int mi = 0; mi < 4; ++mi)
        #pragma unroll
        for (int nj = 0; nj < 4; ++nj) {
            const int cc = (colbase + nj * 16 + fr) & 4095;
            #pragma unroll
            for (int rr = 0; rr < 4; ++rr) {
                const int row = bm0 + wr * 64 + mi * 16 + fq * 4 + rr;
                if (row < M) O[(size_t)row * H_ + cc] = (__bf16)acc[mi][nj][rr];
            }
        }
}

// ---------------------------------------------------------------- O-proj GEMM (256x192, BK=64) + fused lora, f32 out
__global__ __launch_bounds__(512, 2)
void gemm_out(const __bf16* __restrict__ A, const __bf16* __restrict__ Bt,
              const __bf16* __restrict__ TMPo16, const __bf16* __restrict__ WBo16,
              float* __restrict__ C, int M, int Ntot)
{
    const int NY = gridDim.y;
    const int total = gridDim.x * NY;
    const int bid = blockIdx.x * NY + blockIdx.y;
    const int q = total >> 3, r8 = total & 7;
    const int xcd = bid & 7, j = bid >> 3;
    const int swz = (xcd < r8 ? xcd * (q + 1) : r8 * (q + 1) + (xcd - r8) * q) + j;
    const int bm0 = (swz / NY) * 256;
    const int bn0 = (swz % NY) * 192;

    __shared__ __align__(16) __bf16 Asl[2][256 * 64];
    __shared__ __align__(16) __bf16 Bsl[2][192 * 64];

    const int tid = threadIdx.x, lane = tid & 63, wid = tid >> 6;
    const int wr = wid >> 2, wc = wid & 3;
    const int fr = lane & 15, fq = lane >> 4;

    int arow[4], aoff[4], brow[3], boff[3];
    #pragma unroll
    for (int i = 0; i < 4; ++i) {
        const int ci = i * 512 + tid;
        arow[i] = ci >> 3;
        aoff[i] = ((ci & 7) ^ (arow[i] & 7)) * 8;
    }
    #pragma unroll
    for (int i = 0; i < 3; ++i) {
        const int ci = i * 512 + tid;
        brow[i] = ci >> 3;
        boff[i] = ((ci & 7) ^ (brow[i] & 7)) * 8;
    }
    const __bf16* Ab = A  + (size_t)bm0 * H_;
    const __bf16* Bb = Bt + (size_t)bn0 * H_;

    auto stage = [&](int buf, int kt1) {
        const int kb = kt1 * 64;
        #pragma unroll
        for (int i = 0; i < 4; ++i)
            async_cp16(Ab + (size_t)arow[i] * H_ + kb + aoff[i],
                       &Asl[buf][(i * 512 + wid * 64) * 8]);
        #pragma unroll
        for (int i = 0; i < 3; ++i)
            async_cp16(Bb + (size_t)brow[i] * H_ + kb + boff[i],
                       &Bsl[buf][(i * 512 + wid * 64) * 8]);
    };
    auto rdA = [&](int buf, int kh, int mi) -> bf16x8 {
        const int row = wr * 128 + mi * 16 + fr;
        const int kc  = kh * 4 + fq;
        return *(const bf16x8*)&Asl[buf][row * 64 + ((kc ^ (row & 7)) << 3)];
    };
    auto rdB = [&](int buf, int kh, int nj) -> bf16x8 {
        const int row = wc * 48 + nj * 16 + fr;
        const int kc  = kh * 4 + fq;
        return *(const bf16x8*)&Bsl[buf][row * 64 + ((kc ^ (row & 7)) << 3)];
    };

    f32x4 acc[8][3] = {};

    stage(0, 0);
    asm volatile("s_waitcnt vmcnt(0)");
    __builtin_amdgcn_sched_barrier(0);
    __builtin_amdgcn_s_barrier();

    const int NT = H_ / 64;
    for (int kt = 0; kt < NT; ++kt) {
        const int cur = kt & 1, nb = cur ^ 1;
        const bool pf = (kt + 1 < NT);
        bf16x8 af[8], bfr[3];

        #pragma unroll
        for (int mi = 0; mi < 8; ++mi) af[mi] = rdA(cur, 0, mi);
        #pragma unroll
        for (int nj = 0; nj < 3; ++nj) bfr[nj] = rdB(cur, 0, nj);
        if (pf) stage(nb, kt + 1);
        __builtin_amdgcn_s_barrier();
        asm volatile("s_waitcnt lgkmcnt(0)");
        __builtin_amdgcn_sched_barrier(0);
        __builtin_amdgcn_s_setprio(1);
        #pragma unroll
        for (int mi = 0; mi < 8; ++mi)
            #pragma unroll
            for (int nj = 0; nj < 3; ++nj)
                acc[mi][nj] = __builtin_amdgcn_mfma_f32_16x16x32_bf16(af[mi], bfr[nj], acc[mi][nj], 0, 0, 0);
        __builtin_amdgcn_s_setprio(0);
        __builtin_amdgcn_s_barrier();

        #pragma unroll
        for (int mi = 0; mi < 8; ++mi) af[mi] = rdA(cur, 1, mi);
        #pragma unroll
        for (int nj = 0; nj < 3; ++nj) bfr[nj] = rdB(cur, 1, nj);
        __builtin_amdgcn_s_barrier();
        asm volatile("s_waitcnt lgkmcnt(0)");
        __builtin_amdgcn_sched_barrier(0);
        __builtin_amdgcn_s_setprio(1);
        #pragma unroll
        for (int mi = 0; mi < 8; ++mi)
            #pragma unroll
            for (int nj = 0; nj < 3; ++nj)
                acc[mi][nj] = __builtin_amdgcn_mfma_f32_16x16x32_bf16(af[mi], bfr[nj], acc[mi][nj], 0, 0, 0);
        __builtin_amdgcn_s_setprio(0);
        asm volatile("s_waitcnt vmcnt(0)");
        __builtin_amdgcn_sched_barrier(0);
        __builtin_amdgcn_s_barrier();
    }

    const int colw = bn0 + wc * 48;
    bf16x8 aT[8][2], bW[3][2];
    #pragma unroll
    for (int mi = 0; mi < 8; ++mi)
        #pragma unroll
        for (int kh = 0; kh < 2; ++kh)
            aT[mi][kh] = *(const bf16x8*)&TMPo16[(size_t)(bm0 + wr * 128 + mi * 16 + fr) * 64 + kh * 32 + fq * 8];
    #pragma unroll
    for (int nj = 0; nj < 3; ++nj)
        #pragma unroll
        for (int kh = 0; kh < 2; ++kh)
            bW[nj][kh] = *(const bf16x8*)&WBo16[(size_t)(colw + nj * 16 + fr) * 64 + kh * 32 + fq * 8];
    #pragma unroll
    for (int mi = 0; mi < 8; ++mi)
        #pragma unroll
        for (int nj = 0; nj < 3; ++nj) {
            acc[mi][nj] = __builtin_amdgcn_mfma_f32_16x16x32_bf16(aT[mi][0], bW[nj][0], acc[mi][nj], 0, 0, 0);
            acc[mi][nj] = __builtin_amdgcn_mfma_f32_16x16x32_bf16(aT[mi][1], bW[nj][1], acc[mi][nj], 0, 0, 0);
        }
    #pragma unroll
    for (int mi = 0; mi < 8; ++mi)
        #pragma unroll
        for (int nj = 0; nj < 3; ++nj) {
            const int col = colw + nj * 16 + fr;
            if (col < Ntot) {
                #pragma unroll
                for (int rr = 0; rr < 4; ++rr) {
                    const int row = bm0 + wr * 128 + mi * 16 + fq * 4 + rr;
                    if (row < M) C[(size_t)row * H_ + col] = acc[mi][nj][rr];
                }
            }
        }
}

// ---------------------------------------------------------------- RoPE tables
__global__ void rope_table_kernel(float* __restrict__ cost, float* __restrict__ sint)
{
    const int p = blockIdx.x;
    const int i = threadIdx.x;
    const float inv = powf(10000.f, -(float)(2 * i) / (float)HD_);
    const float a = (float)p * inv;
    cost[p * 64 + i] = cosf(a);
    sint[p * 64 + i] = sinf(a);
}

// ---------------------------------------------------------------- rope16
__global__ __launch_bounds__(256)
void rope16_kernel(__bf16* __restrict__ q16, __bf16* __restrict__ k16,
                   const int* __restrict__ kv_lens,
                   const float* __restrict__ cost, const float* __restrict__ sint)
{
    const int r = blockIdx.x;
    int pos; bool dok;
    if (r < DOFF_) {
        if      (r < 1024) pos = r;
        else if (r < 1536) pos = r - 1024;
        else if (r < 2304) pos = r - 1536;
        else               pos = r - 2304;
        dok = true;
    } else {
        pos = kv_lens[r - DOFF_];
        dok = false;
    }
    const int tid = threadIdx.x;
    const int h = tid >> 3, sub = tid & 7;
    const int i0 = sub * 8;
    const size_t b1 = (size_t)r * H_ + h * HD_ + i0;
    const size_t b2 = b1 + 64;

    float cs[8], sn[8];
    #pragma unroll
    for (int j = 0; j < 8; ++j) { cs[j] = cost[pos * 64 + i0 + j]; sn[j] = sint[pos * 64 + i0 + j]; }

    {
        bf16x8 x1 = *(const bf16x8*)&q16[b1], x2 = *(const bf16x8*)&q16[b2];
        bf16x8 o1, o2;
        #pragma unroll
        for (int j = 0; j < 8; ++j) {
            const float f1 = (float)x1[j], f2 = (float)x2[j];
            o1[j] = (__bf16)(f1 * cs[j] - f2 * sn[j]);
            o2[j] = (__bf16)(f2 * cs[j] + f1 * sn[j]);
        }
        *(bf16x8*)&q16[b1] = o1; *(bf16x8*)&q16[b2] = o2;
    }
    if (dok) {
        bf16x8 x1 = *(const bf16x8*)&k16[b1], x2 = *(const bf16x8*)&k16[b2];
        bf16x8 o1, o2;
        #pragma unroll
        for (int j = 0; j < 8; ++j) {
            const float f1 = (float)x1[j], f2 = (float)x2[j];
            o1[j] = (__bf16)(f1 * cs[j] - f2 * sn[j]);
            o2[j] = (__bf16)(f2 * cs[j] + f1 * sn[j]);
        }
        *(bf16x8*)&k16[b1] = o1; *(bf16x8*)&k16[b2] = o2;
    }
}

// ---------------------------------------------------------------- V transpose per head (bf16 in)
__global__ __launch_bounds__(256)
void transpose_v_kernel(const __bf16* __restrict__ v16, __bf16* __restrict__ vT)
{
    __shared__ __bf16 s[64][136];
    const int tb = blockIdx.x;
    const int h  = blockIdx.y;
    const int tid = threadIdx.x;
    #pragma unroll
    for (int i = 0; i < 4; ++i) {
        const int idx = i * 256 + tid;
        const int row = idx >> 4;
        const int c8  = (idx & 15) * 8;
        *(bf16x8*)&s[row][c8] = *(const bf16x8*)&v16[(size_t)(tb * 64 + row) * H_ + h * HD_ + c8];
    }
    __syncthreads();
    #pragma unroll
    for (int i = 0; i < 4; ++i) {
        const int idx = i * 256 + tid;
        const int d = idx >> 3;
        const int c = idx & 7;
        bf16x8 w;
        #pragma unroll
        for (int j = 0; j < 8; ++j) w[j] = s[c * 8 + j][d];
        *(bf16x8*)&vT[(size_t)(h * HD_ + d) * T_ + tb * 64 + c * 8] = w;
    }
}

// ---------------------------------------------------------------- prefill attention (MFMA bf16, flash, K/V dbuf)
__global__ __launch_bounds__(256)
void prefill_attn_mfma(const __bf16* __restrict__ q16, const __bf16* __restrict__ k16,
                       const __bf16* __restrict__ vT, __bf16* __restrict__ attn16)
{
    const int qb = blockIdx.x;
    int soff, qoff;
    if      (qb < 16) { soff = 0;    qoff = qb * 64; }
    else if (qb < 24) { soff = 1024; qoff = (qb - 16) * 64; }
    else if (qb < 36) { soff = 1536; qoff = (qb - 24) * 64; }
    else              { soff = 2304; qoff = (qb - 36) * 64; }
    const int h = blockIdx.y;

    __shared__ __align__(16) __bf16 Kl[2][64 * 128];
    __shared__ __align__(16) __bf16 Vl[2][128 * 64];
    __shared__ __align__(16) __bf16 Pl[4][16 * 64];

    const int tid = threadIdx.x, lane = tid & 63, wid = tid >> 6;
    const int fr = lane & 15, fq = lane >> 4;

    const int grow0 = soff + qoff + wid * 16;
    bf16x8 qf[4];
    #pragma unroll
    for (int ks = 0; ks < 4; ++ks)
        qf[ks] = *(const bf16x8*)&q16[(size_t)(grow0 + fr) * H_ + h * HD_ + ks * 32 + fq * 8];

    auto stageK = [&](int buf, int t) {
        const int kt = t * 64;
        #pragma unroll
        for (int i = 0; i < 4; ++i) {
            const int chunk = i * 256 + tid;
            const int row = chunk >> 4, c = chunk & 15;
            async_cp16(k16 + (size_t)(soff + kt + row) * H_ + h * HD_ + ((c ^ (row & 7)) * 8),
                       Kl[buf] + (size_t)(i * 256 + wid * 64) * 8);
        }
    };
    auto stageV = [&](int buf, int t) {
        const int kt = t * 64;
        #pragma unroll
        for (int i = 0; i < 4; ++i) {
            const int chunk = i * 256 + tid;
            const int row = chunk >> 3, c = chunk & 7;
            async_cp16(vT + (size_t)(h * HD_ + row) * T_ + soff + kt + ((c ^ (row & 7)) * 8),
                       Vl[buf] + (size_t)(i * 256 + wid * 64) * 8);
        }
    };

    float m[4], l[4];
    #pragma unroll
    for (int r = 0; r < 4; ++r) { m[r] = -1e30f; l[r] = 0.f; }
    f32x4 o[8] = {};

    const int ntiles = qoff / 64 + 1;
    stageK(0, 0); stageV(0, 0);
    if (ntiles > 1) {
        stageK(1, 1); stageV(1, 1);
        asm volatile("s_waitcnt vmcnt(8)");
    } else {
        asm volatile("s_waitcnt vmcnt(0)");
    }
    __builtin_amdgcn_sched_barrier(0);
    __builtin_amdgcn_s_barrier();

    for (int t = 0; t < ntiles; ++t) {
        const int b = t & 1;
        const int kt = t * 64;

        f32x4 s[4] = {};
        __builtin_amdgcn_s_setprio(1);
        #pragma unroll
        for (int sub = 0; sub < 4; ++sub)
            #pragma unroll
            for (int ks = 0; ks < 4; ++ks) {
                bf16x8 bk = *(const bf16x8*)&Kl[b][(sub * 16 + fr) * 128 + (((ks * 4 + fq) ^ (fr & 7)) * 8)];
                s[sub] = __builtin_amdgcn_mfma_f32_16x16x32_bf16(qf[ks], bk, s[sub], 0, 0, 0);
            }
        __builtin_amdgcn_s_setprio(0);

        float p[4][4];
        #pragma unroll
        for (int sub = 0; sub < 4; ++sub)
            #pragma unroll
            for (int r = 0; r < 4; ++r) {
                const int qpos = qoff + wid * 16 + fq * 4 + r;
                const int kpos = kt + sub * 16 + fr;
                p[sub][r] = (kpos <= qpos) ? s[sub][r] * SCALE_ : -1e30f;
            }
        // row maxes across the 16 key-lanes
        float tm2[4];
        #pragma unroll
        for (int r = 0; r < 4; ++r) {
            float tm = fmaxf(fmaxf(p[0][r], p[1][r]), fmaxf(p[2][r], p[3][r]));
            tm = fmaxf(tm, __shfl_xor(tm, 1));
            tm = fmaxf(tm, __shfl_xor(tm, 2));
            tm = fmaxf(tm, __shfl_xor(tm, 4));
            tm = fmaxf(tm, __shfl_xor(tm, 8));
            tm2[r] = tm;
        }
        // defer-max (T13): rescale only if some row max grew by > 8
        bool need = false;
        #pragma unroll
        for (int r = 0; r < 4; ++r) need |= (tm2[r] > m[r] + 8.f);
        if (__any(need)) {
            #pragma unroll
            for (int r = 0; r < 4; ++r) {
                const float mn = fmaxf(m[r], tm2[r]);
                const float f  = __expf(m[r] - mn);
                m[r] = mn;
                l[r] *= f;
                #pragma unroll
                for (int c = 0; c < 8; ++c) o[c][r] *= f;
            }
        }
        #pragma unroll
        for (int r = 0; r < 4; ++r) {
            float ls = 0.f;
            #pragma unroll
            for (int sub = 0; sub < 4; ++sub) {
                p[sub][r] = __expf(p[sub][r] - m[r]);
                ls += p[sub][r];
            }
            l[r] += ls;
        }

        #pragma unroll
        for (int sub = 0; sub < 4; ++sub)
            #pragma unroll
            for (int r = 0; r < 4; ++r) {
                const int qr = fq * 4 + r;
                Pl[wid][qr * 64 + ((sub * 16 + fr) ^ ((qr & 7) << 3))] = (__bf16)p[sub][r];
            }
        bf16x8 pa[2];
        #pragma unroll
        for (int a = 0; a < 2; ++a)
            pa[a] = *(const bf16x8*)&Pl[wid][fr * 64 + (((a * 4 + fq) ^ (fr & 7)) * 8)];

        __builtin_amdgcn_s_setprio(1);
        #pragma unroll
        for (int a = 0; a < 2; ++a)
            #pragma unroll
            for (int c = 0; c < 8; ++c) {
                bf16x8 bv = *(const bf16x8*)&Vl[b][(c * 16 + fr) * 64 + (((a * 4 + fq) ^ (fr & 7)) * 8)];
                o[c] = __builtin_amdgcn_mfma_f32_16x16x32_bf16(pa[a], bv, o[c], 0, 0, 0);
            }
        __builtin_amdgcn_s_setprio(0);

        // all waves done with buf b -> refill it with tile t+2; land tile t+1
        __builtin_amdgcn_s_barrier();
        __builtin_amdgcn_sched_barrier(0);
        if (t + 2 < ntiles) { stageK(b, t + 2); stageV(b, t + 2); }
        if (t + 1 < ntiles) {
            if (t + 2 < ntiles) asm volatile("s_waitcnt vmcnt(8)");
            else                asm volatile("s_waitcnt vmcnt(0)");
            __builtin_amdgcn_sched_barrier(0);
            __builtin_amdgcn_s_barrier();
        }
    }

    float inv[4];
    #pragma unroll
    for (int r = 0; r < 4; ++r) {
        float ls = l[r];
        ls += __shfl_xor(ls, 1); ls += __shfl_xor(ls, 2);
        ls += __shfl_xor(ls, 4); ls += __shfl_xor(ls, 8);
        inv[r] = 1.f / ls;
    }
    #pragma unroll
    for (int c = 0; c < 8; ++c)
        #pragma unroll
        for (int r = 0; r < 4; ++r)
            attn16[(size_t)(grow0 + fq * 4 + r) * H_ + h * HD_ + c * 16 + fr] = (__bf16)(o[c][r] * inv[r]);
}

// ---------------------------------------------------------------- decode attention
__global__ __launch_bounds__(256)
void decode_attn_kernel(const __bf16* __restrict__ q16, const __bf16* __restrict__ k16,
                        const __bf16* __restrict__ v16, const float* __restrict__ kc,
                        const float* __restrict__ vc, const int* __restrict__ kv_lens,
                        const float* __restrict__ cost, const float* __restrict__ sint,
                        __bf16* __restrict__ attn16)
{
    const int b = blockIdx.x, h = blockIdx.y;
    const int kvlen = kv_lens[b];
    const int L = kvlen + 1;
    const int tid = threadIdx.x, lane = tid & 63, w = tid >> 6;

    __shared__ float sc_s[LMAX_];
    __shared__ float red[4];
    __shared__ float oacc[HD_];

    const __bf16* qrow = q16 + (size_t)(DOFF_ + b) * H_ + h * HD_;
    const float q1 = (float)qrow[lane], q2 = (float)qrow[lane + 64];
    const __bf16* kdrow = k16 + (size_t)(DOFF_ + b) * H_ + h * HD_;

    for (int l = w; l < L; l += 4) {
        float k1, k2;
        if (l == kvlen) { k1 = (float)kdrow[lane]; k2 = (float)kdrow[lane + 64]; }
        else {
            const float* src = kc + (((size_t)b * LMAX_ + l) * NH_ + h) * HD_;
            k1 = src[lane]; k2 = src[lane + 64];
        }
        const float c = cost[l * 64 + lane], s = sint[l * 64 + lane];
        float d = q1 * (k1 * c - k2 * s) + q2 * (k2 * c + k1 * s);
        #pragma unroll
        for (int off = 1; off < 64; off <<= 1) d += __shfl_xor(d, off);
        if (lane == 0) sc_s[l] = d * SCALE_;
    }
    __syncthreads();

    float mx = -1e30f;
    for (int i = tid; i < L; i += 256) mx = fmaxf(mx, sc_s[i]);
    #pragma unroll
    for (int off = 1; off < 64; off <<= 1) mx = fmaxf(mx, __shfl_xor(mx, off));
    if (lane == 0) red[w] = mx;
    __syncthreads();
    mx = fmaxf(fmaxf(red[0], red[1]), fmaxf(red[2], red[3]));
    __syncthreads();

    float sum = 0.f;
    for (int i = tid; i < L; i += 256) { const float e = __expf(sc_s[i] - mx); sc_s[i] = e; sum += e; }
    #pragma unroll
    for (int off = 1; off < 64; off <<= 1) sum += __shfl_xor(sum, off);
    if (lane == 0) red[w] = sum;
    __syncthreads();
    sum = red[0] + red[1] + red[2] + red[3];
    const float inv = 1.f / sum;

    const int d = tid & 127, team = tid >> 7;
    const __bf16* vdrow = v16 + (size_t)(DOFF_ + b) * H_ + h * HD_;
    float acc = 0.f;
    for (int l = team; l < L; l += 2) {
        float vv;
        if (l == kvlen) vv = (float)vdrow[d];
        else            vv = vc[(((size_t)b * LMAX_ + l) * NH_ + h) * HD_ + d];
        acc += sc_s[l] * vv;
    }
    if (team == 1) oacc[d] = acc;
    __syncthreads();
    if (team == 0) attn16[(size_t)(DOFF_ + b) * H_ + h * HD_ + d] = (__bf16)((acc + oacc[d]) * inv);
}

// ---------------------------------------------------------------- host launch
extern "C" void kernel_launch(void* const* d_in, const int* in_sizes, int n_in,
                              void* d_out, int out_size, void* d_ws, size_t ws_size,
                              hipStream_t stream)
{
    const float* hs     = (const float*)d_in[0];
    const float* wq     = (const float*)d_in[1];
    const float* wk     = (const float*)d_in[2];
    const float* wv     = (const float*)d_in[3];
    const float* wo     = (const float*)d_in[4];
    const float* la_q   = (const float*)d_in[5];
    const float* lb_q   = (const float*)d_in[6];
    const float* la_k   = (const float*)d_in[7];
    const float* lb_k   = (const float*)d_in[8];
    const float* la_v   = (const float*)d_in[9];
    const float* lb_v   = (const float*)d_in[10];
    const float* la_o   = (const float*)d_in[11];
    const float* lb_o   = (const float*)d_in[12];
    const float* kcache = (const float*)d_in[13];
    const float* vcache = (const float*)d_in[14];
    const int*   kvlen  = (const int*)d_in[15];
    float* out = (float*)d_out;

    float*  costab = (float*)d_ws;
    float*  sintab = costab + 1024 * 64;
    __bf16* TMP16  = (__bf16*)(sintab + 1024 * 64);       // [3][MPAD][64]
    __bf16* TMPo16 = TMP16 + (size_t)3 * MPAD_ * 64;      // [MPAD][64]
    __bf16* WB16   = TMPo16 + (size_t)MPAD_ * 64;         // [12288][64]
    __bf16* WBo16  = WB16 + (size_t)3 * H_ * 64;          // [4352][64] (padded)
    __bf16* q16    = WBo16 + (size_t)4352 * 64;           // [T][H]
    __bf16* k16    = q16 + (size_t)T_ * H_;
    __bf16* v16    = k16 + (size_t)T_ * H_;
    __bf16* hsb    = v16 + (size_t)T_ * H_;               // [MPAD][H]: hs bf16, later attn16
    __bf16* wT     = hsb + (size_t)MPAD_ * H_;            // [3][H][H]
    __bf16* vT     = wT + (size_t)H_ * H_;                // reuse wk^T slot after QKV GEMM
    __bf16* attn16 = hsb;

    rope_table_kernel<<<dim3(1024), dim3(64), 0, stream>>>(costab, sintab);
    hs_prep_kernel<<<dim3(T_), dim3(256), 0, stream>>>(hs, hsb, la_q, la_k, la_v, TMP16);
    transpose_bf16_kernel<<<dim3(64, 64, 3), dim3(256), 0, stream>>>(
        wq, wk, wv, wT, wT + (size_t)H_ * H_, wT + (size_t)2 * H_ * H_);
    wb_build_kernel<<<dim3(4, 16), dim3(256), 0, stream>>>(lb_q, lb_k, lb_v, lb_o, WB16, WBo16);
    gemm_qkv<<<dim3(21, 48), dim3(512), 0, stream>>>(
        hsb, wT, TMP16, WB16, q16, k16, v16, T_);
    rope16_kernel<<<dim3(T_), dim3(256), 0, stream>>>(q16, k16, kvlen, costab, sintab);
    transpose_v_kernel<<<dim3(40, 32), dim3(256), 0, stream>>>(v16, vT);
    prefill_attn_mfma<<<dim3(40, 32), dim3(256), 0, stream>>>(q16, k16, vT, attn16);
    decode_attn_kernel<<<dim3(DEC_, NH_), dim3(256), 0, stream>>>(q16, k16, v16, kcache, vcache,
                                                                  kvlen, costab, sintab, attn16);
    transpose_bf16_kernel<<<dim3(64, 64, 1), dim3(256), 0, stream>>>(wo, wo, wo, wT, wT, wT);
    lora_tmp_bf16_kernel<<<dim3(T_), dim3(256), 0, stream>>>(attn16, la_o, TMPo16);
    gemm_out<<<dim3(11, 22), dim3(512), 0, stream>>>(
        attn16, wT, TMPo16, WBo16, out, T_, H_);
}